// Round 9
// baseline (230.581 us; speedup 1.0000x reference)
//
#include <hip/hip_runtime.h>

// Problem constants: B=4, S=2048, D=1024
#define BB 4
#define SS 2048
#define DD 1024
#define MM 8192               // total rows
#define CH 64                 // scan chunks per batch
#define RR 32                 // rows per chunk (CH*RR = SS)
#define PI_F 3.14159265358979323846f

typedef __attribute__((ext_vector_type(8))) short bf16x8;
typedef __attribute__((ext_vector_type(4))) float f32x4;

// ---------------------------------------------------------------------------
// fp32 <-> bf16 helpers (RNE)
// ---------------------------------------------------------------------------
__device__ __forceinline__ unsigned short f2bf(float f) {
  unsigned int u = __float_as_uint(f);
  u = (u + 0x7FFFu + ((u >> 16) & 1u)) >> 16;
  return (unsigned short)u;
}
__device__ __forceinline__ float bf2f(unsigned short h) {
  return __uint_as_float(((unsigned int)h) << 16);
}

// ---------------------------------------------------------------------------
// Twiddle tables in GLOBAL memory (L1-cached, zero LDS/occupancy cost).
// Layout per direction: S=256 @0 (w1[0..255],w2[..],w3[..] = 768), S=64 @768
// (192), S=16 @960 (48), S=4 @1008 (12) -> 1020 float2 = 8160 B.
// Values computed with the EXACT op sequence the stages used inline
// (sincos at the same signed angle + double/triple-angle products) ->
// bit-identical to the proven R6 numerics.
// ---------------------------------------------------------------------------
#define TWN 1020
__host__ __device__ constexpr int twoff(int s) {
  return (s == 256) ? 0 : (s == 64) ? 768 : (s == 16) ? 960 : 1008;
}

template <int S>
__device__ __forceinline__ void tw_fill_one(float2* twf, float2* twi, int j) {
  const int base = twoff(S);
  {
    float s1, c1;
    __sincosf(-2.0f * PI_F * (float)j / (float)(4 * S), &s1, &c1);
    const float c2 = c1 * c1 - s1 * s1, s2 = 2.0f * c1 * s1;
    const float c3 = c1 * c2 - s1 * s2, s3 = c1 * s2 + s1 * c2;
    twf[base + j]         = make_float2(c1, s1);
    twf[base + S + j]     = make_float2(c2, s2);
    twf[base + 2 * S + j] = make_float2(c3, s3);
  }
  {
    float s1, c1;
    __sincosf(2.0f * PI_F * (float)j / (float)(4 * S), &s1, &c1);
    const float c2 = c1 * c1 - s1 * s1, s2 = 2.0f * c1 * s1;
    const float c3 = c1 * c2 - s1 * s2, s3 = c1 * s2 + s1 * c2;
    twi[base + j]         = make_float2(c1, s1);
    twi[base + S + j]     = make_float2(c2, s2);
    twi[base + 2 * S + j] = make_float2(c3, s3);
  }
}

__global__ __launch_bounds__(256) void convert_bf16(
    const float* __restrict__ src, unsigned short* __restrict__ dst) {
  const long i = ((long)blockIdx.x * 256 + threadIdx.x) * 4;
  const float4 v = *(const float4*)&src[i];
  ushort4 o;
  o.x = f2bf(v.x); o.y = f2bf(v.y); o.z = f2bf(v.z); o.w = f2bf(v.w);
  *(ushort4*)&dst[i] = o;
}

__global__ __launch_bounds__(256) void convert_w(
    const float* __restrict__ Wq, const float* __restrict__ Wk,
    const float* __restrict__ Wv, unsigned short* __restrict__ dst,
    float2* __restrict__ twf, float2* __restrict__ twi) {
  const int z = blockIdx.y;
  // Block (0,0) also fills the twiddle tables (runs before bind/unbind on
  // the stream; kernel-boundary coherence makes it visible).
  if (blockIdx.x == 0 && z == 0) {
    const int t = threadIdx.x;
    tw_fill_one<256>(twf, twi, t);
    if (t < 64) tw_fill_one<64>(twf, twi, t);
    if (t < 16) tw_fill_one<16>(twf, twi, t);
    if (t < 4)  tw_fill_one<4>(twf, twi, t);
  }
  const float* src = (z == 0) ? Wq : (z == 1) ? Wk : Wv;
  const long i = ((long)blockIdx.x * 256 + threadIdx.x) * 4;
  const float4 v = *(const float4*)&src[i];
  ushort4 o;
  o.x = f2bf(v.x); o.y = f2bf(v.y); o.z = f2bf(v.z); o.w = f2bf(v.w);
  *(ushort4*)&dst[(size_t)z * DD * DD + i] = o;
}

// ---------------------------------------------------------------------------
// MFMA GEMM — 128x128 tile, BK=64, 4 waves (2M x 2N, 64x64 out/wave),
// 2-phase counted-vmcnt schedule at 2 blocks/CU (LDS 64 KB).
// [R6 structure — best measured. 4/8-barrier variants regressed; barrier
//  crossings (~275cy each) dominate. Frozen.]
// ---------------------------------------------------------------------------
__device__ __forceinline__ void async16(const void* g, void* l) {
  __builtin_amdgcn_global_load_lds(
      (const __attribute__((address_space(1))) void*)g,
      (__attribute__((address_space(3))) void*)l, 16, 0, 0);
}

#define GW(n)  asm volatile("s_waitcnt vmcnt(" #n ")" ::: "memory")
#define BAR()  asm volatile("s_barrier" ::: "memory")
#define SB0()  __builtin_amdgcn_sched_barrier(0)

#define STA(buf, i, T) async16(xb + (size_t)(m0 + 32 * (i)) * DD + (T) * 64 + sOff, \
                               &Als[(buf) * 8192 + (i) * 2048 + slot8])
#define STB(buf, i, T) async16(W + (size_t)(n0 + 32 * (i)) * DD + (T) * 64 + sOff, \
                               &Bls[(buf) * 8192 + (i) * 2048 + slot8])
#define LDA(buf) { _Pragma("unroll") for (int mt = 0; mt < 4; ++mt) { \
    af[mt][0] = *(const bf16x8*)&Als[(buf) * 8192 + aRd + mt * 1024 + qoff0]; \
    af[mt][1] = *(const bf16x8*)&Als[(buf) * 8192 + aRd + mt * 1024 + qoff1]; } }
#define LDB(buf, nt, bank) { \
    bank[0] = *(const bf16x8*)&Bls[(buf) * 8192 + bRd + (nt) * 1024 + qoff0]; \
    bank[1] = *(const bf16x8*)&Bls[(buf) * 8192 + bRd + (nt) * 1024 + qoff1]; }
#define MMA(nt, bank) { __builtin_amdgcn_s_setprio(1); \
    _Pragma("unroll") for (int mt = 0; mt < 4; ++mt) { \
      acc[mt][nt] = __builtin_amdgcn_mfma_f32_16x16x32_bf16(af[mt][0], bank[0], acc[mt][nt], 0, 0, 0); \
      acc[mt][nt] = __builtin_amdgcn_mfma_f32_16x16x32_bf16(af[mt][1], bank[1], acc[mt][nt], 0, 0, 0); } \
    __builtin_amdgcn_s_setprio(0); }

__global__ __launch_bounds__(256, 2) void gemm_mfma(
    const unsigned short* __restrict__ xb,
    const unsigned short* __restrict__ Wb,
    float* __restrict__ outq, unsigned short* __restrict__ KV) {
  const int z = blockIdx.z;
  const unsigned short* W = Wb + (size_t)z * DD * DD;

  __shared__ unsigned short Als[2 * 8192];   // 32 KB
  __shared__ unsigned short Bls[2 * 8192];   // 32 KB

  const int tid  = threadIdx.x;
  const int lane = tid & 63;
  const int w    = tid >> 6;          // wave 0..3
  const int wm   = w >> 1;            // M half (0..1)
  const int wn   = w & 1;             // N half (0..1)
  const int fr   = lane & 15;
  const int kq   = lane >> 4;

  const int m0 = blockIdx.x * 128;
  const int n0 = blockIdx.y * 128;

  // staging geometry: unit = 4 KB = 256 threads x 16 B; 32 rows x 64 cols
  const int srow  = tid >> 3;                  // row within 32-row unit
  const int sq    = (tid & 7) ^ (srow & 7);    // swizzled source quad
  const int slot8 = tid * 8;                   // shorts (lane-linear dest)
  const size_t sOff = (size_t)srow * DD + sq * 8;

  // read-side addressing (same XOR as stage-source swizzle)
  const int qoff0 = ((0 + kq) ^ (fr & 7)) * 8;
  const int qoff1 = ((4 + kq) ^ (fr & 7)) * 8;
  const int aRd = wm * 4096 + fr * 64;
  const int bRd = wn * 4096 + fr * 64;

  f32x4 acc[4][4] = {};
  bf16x8 af[4][2];
  bf16x8 bva[2], bvb[2];

  // Prologue: A(0)x4, B(0)x4, A(1)x4 — order defines the vmcnt queue.
  STA(0, 0, 0); STA(0, 1, 0); STA(0, 2, 0); STA(0, 3, 0);
  STB(0, 0, 0); STB(0, 1, 0); STB(0, 2, 0); STB(0, 3, 0);
  STA(1, 0, 1); STA(1, 1, 1); STA(1, 2, 1); STA(1, 3, 1);

  // Main loop: tiles 0..13 (NT=16), 2 phases/tile, vmcnt(4) once per tile.
  for (int T = 0; T < 14; ++T) {
    const int buf = T & 1;
    // Ph0
    SB0(); GW(4); BAR();
    LDB(buf, 0, bva);
    LDA(buf);
    LDB(buf, 1, bvb);
    STB(buf ^ 1, 0, T + 1); STB(buf ^ 1, 1, T + 1);
    STB(buf ^ 1, 2, T + 1); STB(buf ^ 1, 3, T + 1);
    MMA(0, bva);
    MMA(1, bvb);
    // Ph1
    SB0(); BAR();
    LDB(buf, 2, bva);
    LDB(buf, 3, bvb);
    STA(buf, 0, T + 2); STA(buf, 1, T + 2);
    STA(buf, 2, T + 2); STA(buf, 3, T + 2);
    MMA(2, bva);
    MMA(3, bvb);
  }
  // T = 14 (buf 0): Ph0 stages B(15); Ph1 stages nothing.
  SB0(); GW(4); BAR();
  LDB(0, 0, bva); LDA(0); LDB(0, 1, bvb);
  STB(1, 0, 15); STB(1, 1, 15); STB(1, 2, 15); STB(1, 3, 15);
  MMA(0, bva); MMA(1, bvb);
  SB0(); BAR();
  LDB(0, 2, bva); LDB(0, 3, bvb);
  MMA(2, bva); MMA(3, bvb);
  // T = 15 (buf 1): drain all outstanding stages, no new stages.
  SB0(); GW(0); BAR();
  LDB(1, 0, bva); LDA(1); LDB(1, 1, bvb);
  MMA(0, bva); MMA(1, bvb);
  SB0(); BAR();
  LDB(1, 2, bva); LDB(1, 3, bvb);
  MMA(2, bva); MMA(3, bvb);

  // Epilogue
  const int col = lane & 15;
  const int r0  = (lane >> 4) * 4;
  const int mBase = m0 + wm * 64;
  const int nBase = n0 + wn * 64;
  if (z == 0) {
    #pragma unroll
    for (int mt = 0; mt < 4; ++mt)
      #pragma unroll
      for (int nt = 0; nt < 4; ++nt)
        #pragma unroll
        for (int r = 0; r < 4; ++r)
          outq[(size_t)(mBase + mt * 16 + r0 + r) * DD + nBase + nt * 16 + col] =
              acc[mt][nt][r];
  } else {
    unsigned short* Ck = KV + (size_t)(z - 1) * DD;
    #pragma unroll
    for (int mt = 0; mt < 4; ++mt)
      #pragma unroll
      for (int nt = 0; nt < 4; ++nt)
        #pragma unroll
        for (int r = 0; r < 4; ++r)
          Ck[(size_t)(mBase + mt * 16 + r0 + r) * 2048 + nBase + nt * 16 + col] =
              f2bf(acc[mt][nt][r]);
  }
}

// ---------------------------------------------------------------------------
// Radix-4 FFT, N=1024, 256 threads, 4 complex/thread in registers.
// Twiddles from the global table (3 cached 8B loads/stage replace
// sincos + double/triple-angle chain: ~14 VALU + 2 transcendentals saved
// per stage per thread; values bit-identical).
// ---------------------------------------------------------------------------
__device__ __forceinline__ int pidx(int i) { return i + (i >> 6); }
#define BUFSZ 1040
__device__ __forceinline__ int pidx16(int i) { return i + (i >> 4); }
#define MEMSZ 546   // 513 slots + pads

__device__ __forceinline__ int rev4(int p) {
  unsigned r = __brev((unsigned)p) >> 22;
  return (int)(((r & 0x155u) << 1) | ((r & 0x2AAu) >> 1));
}

__host__ __device__ constexpr int clog2(int s) {
  return (s == 256) ? 8 : (s == 64) ? 6 : (s == 16) ? 4 : (s == 4) ? 2 : 0;
}

template <int S>
__device__ __forceinline__ void fwd_stage(float2 x[4], int t,
                                          const float2* __restrict__ tw) {
  float c1 = 1.0f, s1 = 0.0f, c2 = 1.0f, s2 = 0.0f, c3 = 1.0f, s3 = 0.0f;
  if (S > 1) {
    const int j = t & (S - 1);
    const float2* b = tw + twoff(S);
    const float2 w1 = b[j], w2 = b[S + j], w3 = b[2 * S + j];
    c1 = w1.x; s1 = w1.y; c2 = w2.x; s2 = w2.y; c3 = w3.x; s3 = w3.y;
  }
  const float Ar = x[0].x + x[2].x, Ai = x[0].y + x[2].y;
  const float Br = x[1].x + x[3].x, Bi = x[1].y + x[3].y;
  const float Cr = x[0].x - x[2].x, Ci = x[0].y - x[2].y;
  const float dr = x[1].x - x[3].x, di = x[1].y - x[3].y;
  const float y1r = Cr + di, y1i = Ci - dr;
  const float y2r = Ar - Br, y2i = Ai - Bi;
  const float y3r = Cr - di, y3i = Ci + dr;
  x[0] = make_float2(Ar + Br, Ai + Bi);
  x[1] = make_float2(y1r * c1 - y1i * s1, y1r * s1 + y1i * c1);
  x[2] = make_float2(y2r * c2 - y2i * s2, y2r * s2 + y2i * c2);
  x[3] = make_float2(y3r * c3 - y3i * s3, y3r * s3 + y3i * c3);
}

template <int S>
__device__ __forceinline__ void inv_stage(float2 x[4], int t,
                                          const float2* __restrict__ tw) {
  float c1 = 1.0f, s1 = 0.0f, c2 = 1.0f, s2 = 0.0f, c3 = 1.0f, s3 = 0.0f;
  if (S > 1) {
    const int j = t & (S - 1);
    const float2* b = tw + twoff(S);
    const float2 w1 = b[j], w2 = b[S + j], w3 = b[2 * S + j];
    c1 = w1.x; s1 = w1.y; c2 = w2.x; s2 = w2.y; c3 = w3.x; s3 = w3.y;
  }
  const float u0r = x[0].x,                   u0i = x[0].y;
  const float u1r = x[1].x * c1 - x[1].y * s1, u1i = x[1].x * s1 + x[1].y * c1;
  const float u2r = x[2].x * c2 - x[2].y * s2, u2i = x[2].x * s2 + x[2].y * c2;
  const float u3r = x[3].x * c3 - x[3].y * s3, u3i = x[3].x * s3 + x[3].y * c3;
  const float Er = u0r + u2r, Ei = u0i + u2i;
  const float Fr = u0r - u2r, Fi = u0i - u2i;
  const float Gr = u1r + u3r, Gi = u1i + u3i;
  const float Hr = u1r - u3r, Hi = u1i - u3i;
  x[0] = make_float2(Er + Gr, Ei + Gi);
  x[1] = make_float2(Fr - Hi, Fi + Hr);
  x[2] = make_float2(Er - Gr, Ei - Gi);
  x[3] = make_float2(Fr + Hi, Fi - Hr);
}

template <int SW, int SR>
__device__ __forceinline__ void xchg(float2* buf, float2 x[4], int t) {
  constexpr int LW2 = clog2(SW), LR = clog2(SR);
  #pragma unroll
  for (int n = 0; n < 4; ++n)
    buf[pidx(((t >> LW2) << (LW2 + 2)) + (t & (SW - 1)) + n * SW)] = x[n];
  __syncthreads();
  #pragma unroll
  for (int n = 0; n < 4; ++n)
    x[n] = buf[pidx(((t >> LR) << (LR + 2)) + (t & (SR - 1)) + n * SR)];
  __syncthreads();
}

__device__ __forceinline__ void fwd_fft(float2* buf, float2 x[4], int t,
                                        const float2* __restrict__ tw) {
  fwd_stage<256>(x, t, tw); xchg<256, 64>(buf, x, t);
  fwd_stage<64>(x, t, tw);  xchg<64, 16>(buf, x, t);
  fwd_stage<16>(x, t, tw);  xchg<16, 4>(buf, x, t);
  fwd_stage<4>(x, t, tw);   xchg<4, 1>(buf, x, t);
  fwd_stage<1>(x, t, tw);
  #pragma unroll
  for (int n = 0; n < 4; ++n) buf[pidx(4 * t + n)] = x[n];
  __syncthreads();
}

// ---------------------------------------------------------------------------
// Bind (in place): KV row [k|v] bf16 (4 KB) -> one FFT of k+iv, Hermitian
// split, P = fk*fv packed to HALF spectrum over the same 4 KB:
//   slot 0 = (P[0], P[512]) (both exactly real), slot s = P[s], s=1..511.
// ---------------------------------------------------------------------------
__global__ __launch_bounds__(256) void bind_kernel(
    unsigned short* __restrict__ KV, const float2* __restrict__ twf) {
  __shared__ float2 buf[BUFSZ];
  const int t = threadIdx.x;
  unsigned short* row = KV + (long)blockIdx.x * 2048;

  float2 x[4];
  #pragma unroll
  for (int n = 0; n < 4; ++n) {
    const int i = t + 256 * n;
    x[n] = make_float2(bf2f(row[i]), bf2f(row[1024 + i]));   // k + i*v
  }
  fwd_fft(buf, x, t, twf);

  float2* Prow = (float2*)row;
  #pragma unroll
  for (int m = 0; m < 2; ++m) {
    const int s = t + 256 * m;
    if (s == 0) {
      const float2 W0   = buf[pidx(0)];
      const float2 W512 = buf[pidx(2)];
      Prow[0] = make_float2(W0.x * W0.y, W512.x * W512.y);
    } else {
      const int p1 = rev4(s);
      const int p2 = rev4(1024 - s);
      const float2 F1 = buf[pidx(p1)], F2 = buf[pidx(p2)];
      const float fkr = 0.5f * (F1.x + F2.x), fki = 0.5f * (F1.y - F2.y);
      const float fvr = 0.5f * (F1.y + F2.y), fvi = 0.5f * (F2.x - F1.x);
      Prow[s] = make_float2(fkr * fvr - fki * fvi, fkr * fvi + fki * fvr);
    }
  }
}

// ---------------------------------------------------------------------------
// Causal cumsum over s per packed bin; grids cover nB batches (gridDim.y=2*nB).
// Loads batched 8-deep (breaks dependent-latency chain); order preserved.
// ---------------------------------------------------------------------------
__global__ __launch_bounds__(256) void scan_chunk_sum(
    const float2* __restrict__ P, float2* __restrict__ csum) {
  const int chunk = blockIdx.x;
  const int batch = blockIdx.y >> 1;
  const int f = (blockIdx.y & 1) * 256 + threadIdx.x;
  long base = ((long)batch * SS + (long)chunk * RR) * 512 + f;
  float sr = 0.0f, si = 0.0f;
  #pragma unroll
  for (int i0 = 0; i0 < RR; i0 += 8) {
    float2 p[8];
    #pragma unroll
    for (int j = 0; j < 8; ++j) p[j] = P[base + (long)(i0 + j) * 512];
    #pragma unroll
    for (int j = 0; j < 8; ++j) { sr += p[j].x; si += p[j].y; }
  }
  csum[((long)batch * CH + chunk) * 512 + f] = make_float2(sr, si);
}

// Wave-parallel exclusive scan over the 64 chunks: one wave per (batch,bin)
// column, lane = chunk.
__global__ __launch_bounds__(256) void scan_chunk_scan(float2* csum) {
  const int col   = blockIdx.x * 4 + (threadIdx.x >> 6);  // (batch,f) column
  const int batch = col >> 9;
  const int f     = col & 511;
  const int c     = threadIdx.x & 63;                     // lane = chunk
  const long idx  = ((long)batch * CH + c) * 512 + f;
  const float2 v  = csum[idx];
  float rr = v.x, ri = v.y;
  #pragma unroll
  for (int d = 1; d < 64; d <<= 1) {
    const float ox = __shfl_up(rr, d);
    const float oy = __shfl_up(ri, d);
    if (c >= d) { rr += ox; ri += oy; }
  }
  // inclusive -> exclusive via lane shift
  float ex = __shfl_up(rr, 1);
  float ey = __shfl_up(ri, 1);
  if (c == 0) { ex = 0.0f; ey = 0.0f; }
  csum[idx] = make_float2(ex, ey);
}

__global__ __launch_bounds__(256) void scan_apply(
    float2* __restrict__ P, const float2* __restrict__ csum) {
  const int chunk = blockIdx.x;
  const int batch = blockIdx.y >> 1;
  const int f = (blockIdx.y & 1) * 256 + threadIdx.x;
  float2 off = csum[((long)batch * CH + chunk) * 512 + f];
  float ar = off.x, ai = off.y;
  long base = ((long)batch * SS + (long)chunk * RR) * 512 + f;
  #pragma unroll
  for (int i0 = 0; i0 < RR; i0 += 8) {
    float2 p[8];
    #pragma unroll
    for (int j = 0; j < 8; ++j) p[j] = P[base + (long)(i0 + j) * 512];
    #pragma unroll
    for (int j = 0; j < 8; ++j) {
      ar += p[j].x; ai += p[j].y;
      P[base + (long)(i0 + j) * 512] = make_float2(ar, ai);
    }
  }
}

// ---------------------------------------------------------------------------
// Unbind, 2 rows/block (in place on d_out). mem rows Hermitian-packed;
// unpack into LDS, gather with predicated conj; one fwd FFT (q0+iq1),
// one inv FFT (z0+iz1).
// ---------------------------------------------------------------------------
__global__ __launch_bounds__(256) void unbind_kernel(
    float* __restrict__ qout, const float2* __restrict__ mem,
    const float2* __restrict__ twf, const float2* __restrict__ twi) {
  __shared__ float2 buf[BUFSZ];
  __shared__ float2 m0s[MEMSZ], m1s[MEMSZ];
  const int t = threadIdx.x;
  const long r0 = (long)blockIdx.x * 2;
  float* row0 = qout + r0 * DD;
  float* row1 = row0 + DD;
  const float2* mem0 = mem + r0 * 512;
  const float2* mem1 = mem0 + 512;

  float2 x[4];
  #pragma unroll
  for (int n = 0; n < 4; ++n) {
    const int i = t + 256 * n;
    x[n] = make_float2(row0[i], row1[i]);        // q0 + i*q1
  }
  #pragma unroll
  for (int n = 0; n < 2; ++n) {
    const int s = t + 256 * n;
    const float2 a = mem0[s], b = mem1[s];
    if (s == 0) {
      m0s[pidx16(0)]   = make_float2(a.x, 0.0f);
      m0s[pidx16(512)] = make_float2(a.y, 0.0f);
      m1s[pidx16(0)]   = make_float2(b.x, 0.0f);
      m1s[pidx16(512)] = make_float2(b.y, 0.0f);
    } else {
      m0s[pidx16(s)] = a;
      m1s[pidx16(s)] = b;
    }
  }
  fwd_fft(buf, x, t, twf);   // internal barriers order the m*s writes too

  float2 z[4];
  #pragma unroll
  for (int m = 0; m < 4; ++m) {
    const int p   = t + 256 * m;
    const int bin = rev4(p);
    const int p2  = rev4((1024 - bin) & 1023);
    const float2 F1 = buf[pidx(p)], F2 = buf[pidx(p2)];
    const float q0r = 0.5f * (F1.x + F2.x), q0i = 0.5f * (F1.y - F2.y);
    const float q1r = 0.5f * (F1.y + F2.y), q1i = 0.5f * (F2.x - F1.x);
    const int  ix = (bin <= 512) ? bin : 1024 - bin;
    const float sg = (bin <= 512) ? 1.0f : -1.0f;
    float2 m0 = m0s[pidx16(ix)], m1 = m1s[pidx16(ix)];
    m0.y *= sg; m1.y *= sg;
    const float z0r = m0.x * q0r + m0.y * q0i, z0i = m0.y * q0r - m0.x * q0i;
    const float z1r = m1.x * q1r + m1.y * q1i, z1i = m1.y * q1r - m1.x * q1i;
    z[m] = make_float2(z0r - z1i, z0i + z1r);    // z0 + i*z1
  }
  __syncthreads();
  #pragma unroll
  for (int m = 0; m < 4; ++m) buf[pidx(t + 256 * m)] = z[m];
  __syncthreads();
  #pragma unroll
  for (int n = 0; n < 4; ++n) x[n] = buf[pidx(4 * t + n)];

  inv_stage<1>(x, t, twi);   xchg<1, 4>(buf, x, t);
  inv_stage<4>(x, t, twi);   xchg<4, 16>(buf, x, t);
  inv_stage<16>(x, t, twi);  xchg<16, 64>(buf, x, t);
  inv_stage<64>(x, t, twi);  xchg<64, 256>(buf, x, t);
  inv_stage<256>(x, t, twi);

  const float sc = 1.0f / 1024.0f;
  #pragma unroll
  for (int n = 0; n < 4; ++n) {
    const int i = t + 256 * n;
    row0[i] = x[n].x * sc;
    row1[i] = x[n].y * sc;
  }
}

// ---------------------------------------------------------------------------
extern "C" void kernel_launch(void* const* d_in, const int* in_sizes, int n_in,
                              void* d_out, int out_size, void* d_ws, size_t ws_size,
                              hipStream_t stream) {
  (void)in_sizes; (void)n_in; (void)out_size;
  const float* x  = (const float*)d_in[0];
  const float* Wq = (const float*)d_in[1];
  const float* Wk = (const float*)d_in[2];
  const float* Wv = (const float*)d_in[3];
  float* out = (float*)d_out;

  // ws layout for MH rows/pass, nB batches/pass:
  //   tw   : 2 tables x 1020 float2  = 16 KB (rounded)
  //   Wb   : 3*1024*1024 bf16        = 6.29 MB
  //   xb   : MH*1024 bf16
  //   KV/P : MH rows * 4 KB
  //   csum : nB*64*512 float2
  // Single-pass (MH=8192): 57.69 MB; two-pass (MH=4096): 32.0 MB. Branch on
  // ws_size — constant across calls, so graph-safe.
  const size_t twbytes = 16384;
  const size_t wbytes  = (size_t)3 * DD * DD * 2;
  auto need = [&](size_t MHr, size_t nB) {
    return twbytes + wbytes + MHr * DD * 2 + MHr * 4096 + nB * CH * 512 * 8;
  };
  const int nPass = (ws_size >= need(8192, 4)) ? 1 : 2;
  const size_t MH = MM / nPass;          // rows per pass
  const int    nB = BB / nPass;          // batches per pass

  char* ws = (char*)d_ws;
  float2* twf = (float2*)ws;
  float2* twi = (float2*)(ws + TWN * 8);
  unsigned short* Wb = (unsigned short*)(ws + twbytes);
  unsigned short* xb = (unsigned short*)(ws + twbytes + wbytes);
  unsigned short* KV = (unsigned short*)(ws + twbytes + wbytes + MH * DD * 2);
  float2*       csum = (float2*)((char*)KV + MH * 4096);

  convert_w<<<dim3(DD * DD / 1024, 3), 256, 0, stream>>>(Wq, Wk, Wv, Wb, twf, twi);

  for (int h = 0; h < nPass; ++h) {
    const float* xh   = x   + (size_t)h * MH * DD;
    float*       outh = out + (size_t)h * MH * DD;

    convert_bf16<<<MH * DD / 1024, 256, 0, stream>>>(xh, xb);
    gemm_mfma<<<dim3(MH / 128, DD / 128, 3), dim3(256), 0, stream>>>(xb, Wb, outh, KV);
    bind_kernel<<<MH, 256, 0, stream>>>(KV, twf);
    scan_chunk_sum<<<dim3(CH, nB * 2), 256, 0, stream>>>((const float2*)KV, csum);
    scan_chunk_scan<<<nB * 128, 256, 0, stream>>>(csum);
    scan_apply<<<dim3(CH, nB * 2), 256, 0, stream>>>((float2*)KV, csum);
    unbind_kernel<<<MH / 2, 256, 0, stream>>>(outh, (const float2*)KV, twf, twi);
  }
}

// Round 10
// 224.623 us; speedup vs baseline: 1.0265x; 1.0265x over previous
//
#include <hip/hip_runtime.h>

// Problem constants: B=4, S=2048, D=1024
#define BB 4
#define SS 2048
#define DD 1024
#define MM 8192               // total rows
#define CH 64                 // scan chunks per batch
#define RR 32                 // rows per chunk (CH*RR = SS)
#define PI_F 3.14159265358979323846f

typedef __attribute__((ext_vector_type(8))) short bf16x8;
typedef __attribute__((ext_vector_type(4))) float f32x4;

// ---------------------------------------------------------------------------
// fp32 <-> bf16 helpers (RNE)
// ---------------------------------------------------------------------------
__device__ __forceinline__ unsigned short f2bf(float f) {
  unsigned int u = __float_as_uint(f);
  u = (u + 0x7FFFu + ((u >> 16) & 1u)) >> 16;
  return (unsigned short)u;
}
__device__ __forceinline__ float bf2f(unsigned short h) {
  return __uint_as_float(((unsigned int)h) << 16);
}

__global__ __launch_bounds__(256) void convert_bf16(
    const float* __restrict__ src, unsigned short* __restrict__ dst) {
  const long i = ((long)blockIdx.x * 256 + threadIdx.x) * 4;
  const float4 v = *(const float4*)&src[i];
  ushort4 o;
  o.x = f2bf(v.x); o.y = f2bf(v.y); o.z = f2bf(v.z); o.w = f2bf(v.w);
  *(ushort4*)&dst[i] = o;
}

__global__ __launch_bounds__(256) void convert_w(
    const float* __restrict__ Wq, const float* __restrict__ Wk,
    const float* __restrict__ Wv, unsigned short* __restrict__ dst) {
  const int z = blockIdx.y;
  const float* src = (z == 0) ? Wq : (z == 1) ? Wk : Wv;
  const long i = ((long)blockIdx.x * 256 + threadIdx.x) * 4;
  const float4 v = *(const float4*)&src[i];
  ushort4 o;
  o.x = f2bf(v.x); o.y = f2bf(v.y); o.z = f2bf(v.z); o.w = f2bf(v.w);
  *(ushort4*)&dst[(size_t)z * DD * DD + i] = o;
}

// ---------------------------------------------------------------------------
// MFMA GEMM — 128x128 tile, BK=64, 4 waves (2M x 2N, 64x64 out/wave),
// 2-phase counted-vmcnt schedule at 2 blocks/CU (LDS 64 KB).
// [R6 structure — best measured. 4/8-barrier variants regressed; barrier
//  crossings (~275cy each) dominate. Frozen.]
// ---------------------------------------------------------------------------
__device__ __forceinline__ void async16(const void* g, void* l) {
  __builtin_amdgcn_global_load_lds(
      (const __attribute__((address_space(1))) void*)g,
      (__attribute__((address_space(3))) void*)l, 16, 0, 0);
}

#define GW(n)  asm volatile("s_waitcnt vmcnt(" #n ")" ::: "memory")
#define BAR()  asm volatile("s_barrier" ::: "memory")
#define SB0()  __builtin_amdgcn_sched_barrier(0)

#define STA(buf, i, T) async16(xb + (size_t)(m0 + 32 * (i)) * DD + (T) * 64 + sOff, \
                               &Als[(buf) * 8192 + (i) * 2048 + slot8])
#define STB(buf, i, T) async16(W + (size_t)(n0 + 32 * (i)) * DD + (T) * 64 + sOff, \
                               &Bls[(buf) * 8192 + (i) * 2048 + slot8])
#define LDA(buf) { _Pragma("unroll") for (int mt = 0; mt < 4; ++mt) { \
    af[mt][0] = *(const bf16x8*)&Als[(buf) * 8192 + aRd + mt * 1024 + qoff0]; \
    af[mt][1] = *(const bf16x8*)&Als[(buf) * 8192 + aRd + mt * 1024 + qoff1]; } }
#define LDB(buf, nt, bank) { \
    bank[0] = *(const bf16x8*)&Bls[(buf) * 8192 + bRd + (nt) * 1024 + qoff0]; \
    bank[1] = *(const bf16x8*)&Bls[(buf) * 8192 + bRd + (nt) * 1024 + qoff1]; }
#define MMA(nt, bank) { __builtin_amdgcn_s_setprio(1); \
    _Pragma("unroll") for (int mt = 0; mt < 4; ++mt) { \
      acc[mt][nt] = __builtin_amdgcn_mfma_f32_16x16x32_bf16(af[mt][0], bank[0], acc[mt][nt], 0, 0, 0); \
      acc[mt][nt] = __builtin_amdgcn_mfma_f32_16x16x32_bf16(af[mt][1], bank[1], acc[mt][nt], 0, 0, 0); } \
    __builtin_amdgcn_s_setprio(0); }

__global__ __launch_bounds__(256, 2) void gemm_mfma(
    const unsigned short* __restrict__ xb,
    const unsigned short* __restrict__ Wb,
    float* __restrict__ outq, unsigned short* __restrict__ KV) {
  const int z = blockIdx.z;
  const unsigned short* W = Wb + (size_t)z * DD * DD;

  __shared__ unsigned short Als[2 * 8192];   // 32 KB
  __shared__ unsigned short Bls[2 * 8192];   // 32 KB

  const int tid  = threadIdx.x;
  const int lane = tid & 63;
  const int w    = tid >> 6;          // wave 0..3
  const int wm   = w >> 1;            // M half (0..1)
  const int wn   = w & 1;             // N half (0..1)
  const int fr   = lane & 15;
  const int kq   = lane >> 4;

  const int m0 = blockIdx.x * 128;
  const int n0 = blockIdx.y * 128;

  // staging geometry: unit = 4 KB = 256 threads x 16 B; 32 rows x 64 cols
  const int srow  = tid >> 3;                  // row within 32-row unit
  const int sq    = (tid & 7) ^ (srow & 7);    // swizzled source quad
  const int slot8 = tid * 8;                   // shorts (lane-linear dest)
  const size_t sOff = (size_t)srow * DD + sq * 8;

  // read-side addressing (same XOR as stage-source swizzle)
  const int qoff0 = ((0 + kq) ^ (fr & 7)) * 8;
  const int qoff1 = ((4 + kq) ^ (fr & 7)) * 8;
  const int aRd = wm * 4096 + fr * 64;
  const int bRd = wn * 4096 + fr * 64;

  f32x4 acc[4][4] = {};
  bf16x8 af[4][2];
  bf16x8 bva[2], bvb[2];

  // Prologue: A(0)x4, B(0)x4, A(1)x4 — order defines the vmcnt queue.
  STA(0, 0, 0); STA(0, 1, 0); STA(0, 2, 0); STA(0, 3, 0);
  STB(0, 0, 0); STB(0, 1, 0); STB(0, 2, 0); STB(0, 3, 0);
  STA(1, 0, 1); STA(1, 1, 1); STA(1, 2, 1); STA(1, 3, 1);

  // Main loop: tiles 0..13 (NT=16), 2 phases/tile, vmcnt(4) once per tile.
  for (int T = 0; T < 14; ++T) {
    const int buf = T & 1;
    // Ph0
    SB0(); GW(4); BAR();
    LDB(buf, 0, bva);
    LDA(buf);
    LDB(buf, 1, bvb);
    STB(buf ^ 1, 0, T + 1); STB(buf ^ 1, 1, T + 1);
    STB(buf ^ 1, 2, T + 1); STB(buf ^ 1, 3, T + 1);
    MMA(0, bva);
    MMA(1, bvb);
    // Ph1
    SB0(); BAR();
    LDB(buf, 2, bva);
    LDB(buf, 3, bvb);
    STA(buf, 0, T + 2); STA(buf, 1, T + 2);
    STA(buf, 2, T + 2); STA(buf, 3, T + 2);
    MMA(2, bva);
    MMA(3, bvb);
  }
  // T = 14 (buf 0): Ph0 stages B(15); Ph1 stages nothing.
  SB0(); GW(4); BAR();
  LDB(0, 0, bva); LDA(0); LDB(0, 1, bvb);
  STB(1, 0, 15); STB(1, 1, 15); STB(1, 2, 15); STB(1, 3, 15);
  MMA(0, bva); MMA(1, bvb);
  SB0(); BAR();
  LDB(0, 2, bva); LDB(0, 3, bvb);
  MMA(2, bva); MMA(3, bvb);
  // T = 15 (buf 1): drain all outstanding stages, no new stages.
  SB0(); GW(0); BAR();
  LDB(1, 0, bva); LDA(1); LDB(1, 1, bvb);
  MMA(0, bva); MMA(1, bvb);
  SB0(); BAR();
  LDB(1, 2, bva); LDB(1, 3, bvb);
  MMA(2, bva); MMA(3, bvb);

  // Epilogue
  const int col = lane & 15;
  const int r0  = (lane >> 4) * 4;
  const int mBase = m0 + wm * 64;
  const int nBase = n0 + wn * 64;
  if (z == 0) {
    #pragma unroll
    for (int mt = 0; mt < 4; ++mt)
      #pragma unroll
      for (int nt = 0; nt < 4; ++nt)
        #pragma unroll
        for (int r = 0; r < 4; ++r)
          outq[(size_t)(mBase + mt * 16 + r0 + r) * DD + nBase + nt * 16 + col] =
              acc[mt][nt][r];
  } else {
    unsigned short* Ck = KV + (size_t)(z - 1) * DD;
    #pragma unroll
    for (int mt = 0; mt < 4; ++mt)
      #pragma unroll
      for (int nt = 0; nt < 4; ++nt)
        #pragma unroll
        for (int r = 0; r < 4; ++r)
          Ck[(size_t)(mBase + mt * 16 + r0 + r) * 2048 + nBase + nt * 16 + col] =
              f2bf(acc[mt][nt][r]);
  }
}

// ---------------------------------------------------------------------------
// Radix-4 FFT, N=1024, 256 threads, 4 complex/thread in registers (proven
// sincos version — both LDS and global twiddle tables measured slower:
// table adds dependent loads on the stage critical path; v_sin/v_cos are
// single-instruction on gfx950). Forward DIF -> base-4 digit-reversed
// order; inverse DIT back.
// ---------------------------------------------------------------------------
__device__ __forceinline__ int pidx(int i) { return i + (i >> 6); }
#define BUFSZ 1040
__device__ __forceinline__ int pidx16(int i) { return i + (i >> 4); }
#define MEMSZ 546   // 513 slots + pads

__device__ __forceinline__ int rev4(int p) {
  unsigned r = __brev((unsigned)p) >> 22;
  return (int)(((r & 0x155u) << 1) | ((r & 0x2AAu) >> 1));
}

__host__ __device__ constexpr int clog2(int s) {
  return (s == 256) ? 8 : (s == 64) ? 6 : (s == 16) ? 4 : (s == 4) ? 2 : 0;
}

template <int S>
__device__ __forceinline__ void fwd_stage(float2 x[4], int t) {
  float c1 = 1.0f, s1 = 0.0f;
  if (S > 1) {
    const int j = t & (S - 1);
    __sincosf(-2.0f * PI_F * (float)j / (float)(4 * S), &s1, &c1);
  }
  const float c2 = c1 * c1 - s1 * s1, s2 = 2.0f * c1 * s1;
  const float c3 = c1 * c2 - s1 * s2, s3 = c1 * s2 + s1 * c2;
  const float Ar = x[0].x + x[2].x, Ai = x[0].y + x[2].y;
  const float Br = x[1].x + x[3].x, Bi = x[1].y + x[3].y;
  const float Cr = x[0].x - x[2].x, Ci = x[0].y - x[2].y;
  const float dr = x[1].x - x[3].x, di = x[1].y - x[3].y;
  const float y1r = Cr + di, y1i = Ci - dr;
  const float y2r = Ar - Br, y2i = Ai - Bi;
  const float y3r = Cr - di, y3i = Ci + dr;
  x[0] = make_float2(Ar + Br, Ai + Bi);
  x[1] = make_float2(y1r * c1 - y1i * s1, y1r * s1 + y1i * c1);
  x[2] = make_float2(y2r * c2 - y2i * s2, y2r * s2 + y2i * c2);
  x[3] = make_float2(y3r * c3 - y3i * s3, y3r * s3 + y3i * c3);
}

template <int S>
__device__ __forceinline__ void inv_stage(float2 x[4], int t) {
  float c1 = 1.0f, s1 = 0.0f;
  if (S > 1) {
    const int j = t & (S - 1);
    __sincosf(2.0f * PI_F * (float)j / (float)(4 * S), &s1, &c1);
  }
  const float c2 = c1 * c1 - s1 * s1, s2 = 2.0f * c1 * s1;
  const float c3 = c1 * c2 - s1 * s2, s3 = c1 * s2 + s1 * c2;
  const float u0r = x[0].x,                   u0i = x[0].y;
  const float u1r = x[1].x * c1 - x[1].y * s1, u1i = x[1].x * s1 + x[1].y * c1;
  const float u2r = x[2].x * c2 - x[2].y * s2, u2i = x[2].x * s2 + x[2].y * c2;
  const float u3r = x[3].x * c3 - x[3].y * s3, u3i = x[3].x * s3 + x[3].y * c3;
  const float Er = u0r + u2r, Ei = u0i + u2i;
  const float Fr = u0r - u2r, Fi = u0i - u2i;
  const float Gr = u1r + u3r, Gi = u1i + u3i;
  const float Hr = u1r - u3r, Hi = u1i - u3i;
  x[0] = make_float2(Er + Gr, Ei + Gi);
  x[1] = make_float2(Fr - Hi, Fi + Hr);
  x[2] = make_float2(Er - Gr, Ei - Gi);
  x[3] = make_float2(Fr + Hi, Fi - Hr);
}

template <int SW, int SR>
__device__ __forceinline__ void xchg(float2* buf, float2 x[4], int t) {
  constexpr int LW2 = clog2(SW), LR = clog2(SR);
  #pragma unroll
  for (int n = 0; n < 4; ++n)
    buf[pidx(((t >> LW2) << (LW2 + 2)) + (t & (SW - 1)) + n * SW)] = x[n];
  __syncthreads();
  #pragma unroll
  for (int n = 0; n < 4; ++n)
    x[n] = buf[pidx(((t >> LR) << (LR + 2)) + (t & (SR - 1)) + n * SR)];
  __syncthreads();
}

__device__ __forceinline__ void fwd_fft(float2* buf, float2 x[4], int t) {
  fwd_stage<256>(x, t); xchg<256, 64>(buf, x, t);
  fwd_stage<64>(x, t);  xchg<64, 16>(buf, x, t);
  fwd_stage<16>(x, t);  xchg<16, 4>(buf, x, t);
  fwd_stage<4>(x, t);   xchg<4, 1>(buf, x, t);
  fwd_stage<1>(x, t);
  #pragma unroll
  for (int n = 0; n < 4; ++n) buf[pidx(4 * t + n)] = x[n];
  __syncthreads();
}

// ---------------------------------------------------------------------------
// Bind (in place): KV row [k|v] bf16 (4 KB) -> one FFT of k+iv, Hermitian
// split, P = fk*fv packed to HALF spectrum over the same 4 KB:
//   slot 0 = (P[0], P[512]) (both exactly real), slot s = P[s], s=1..511.
// ---------------------------------------------------------------------------
__global__ __launch_bounds__(256) void bind_kernel(unsigned short* __restrict__ KV) {
  __shared__ float2 buf[BUFSZ];
  const int t = threadIdx.x;
  unsigned short* row = KV + (long)blockIdx.x * 2048;

  float2 x[4];
  #pragma unroll
  for (int n = 0; n < 4; ++n) {
    const int i = t + 256 * n;
    x[n] = make_float2(bf2f(row[i]), bf2f(row[1024 + i]));   // k + i*v
  }
  fwd_fft(buf, x, t);

  float2* Prow = (float2*)row;
  #pragma unroll
  for (int m = 0; m < 2; ++m) {
    const int s = t + 256 * m;
    if (s == 0) {
      const float2 W0   = buf[pidx(0)];
      const float2 W512 = buf[pidx(2)];
      Prow[0] = make_float2(W0.x * W0.y, W512.x * W512.y);
    } else {
      const int p1 = rev4(s);
      const int p2 = rev4(1024 - s);
      const float2 F1 = buf[pidx(p1)], F2 = buf[pidx(p2)];
      const float fkr = 0.5f * (F1.x + F2.x), fki = 0.5f * (F1.y - F2.y);
      const float fvr = 0.5f * (F1.y + F2.y), fvi = 0.5f * (F2.x - F1.x);
      Prow[s] = make_float2(fkr * fvr - fki * fvi, fkr * fvi + fki * fvr);
    }
  }
}

// ---------------------------------------------------------------------------
// Causal cumsum over s per packed bin; grids cover nB batches (gridDim.y=2*nB).
// Loads batched 8-deep (breaks dependent-latency chain); order preserved.
// ---------------------------------------------------------------------------
__global__ __launch_bounds__(256) void scan_chunk_sum(
    const float2* __restrict__ P, float2* __restrict__ csum) {
  const int chunk = blockIdx.x;
  const int batch = blockIdx.y >> 1;
  const int f = (blockIdx.y & 1) * 256 + threadIdx.x;
  long base = ((long)batch * SS + (long)chunk * RR) * 512 + f;
  float sr = 0.0f, si = 0.0f;
  #pragma unroll
  for (int i0 = 0; i0 < RR; i0 += 8) {
    float2 p[8];
    #pragma unroll
    for (int j = 0; j < 8; ++j) p[j] = P[base + (long)(i0 + j) * 512];
    #pragma unroll
    for (int j = 0; j < 8; ++j) { sr += p[j].x; si += p[j].y; }
  }
  csum[((long)batch * CH + chunk) * 512 + f] = make_float2(sr, si);
}

// Wave-parallel exclusive scan over the 64 chunks: one wave per (batch,bin)
// column, lane = chunk.
__global__ __launch_bounds__(256) void scan_chunk_scan(float2* csum) {
  const int col   = blockIdx.x * 4 + (threadIdx.x >> 6);  // (batch,f) column
  const int batch = col >> 9;
  const int f     = col & 511;
  const int c     = threadIdx.x & 63;                     // lane = chunk
  const long idx  = ((long)batch * CH + c) * 512 + f;
  const float2 v  = csum[idx];
  float rr = v.x, ri = v.y;
  #pragma unroll
  for (int d = 1; d < 64; d <<= 1) {
    const float ox = __shfl_up(rr, d);
    const float oy = __shfl_up(ri, d);
    if (c >= d) { rr += ox; ri += oy; }
  }
  // inclusive -> exclusive via lane shift
  float ex = __shfl_up(rr, 1);
  float ey = __shfl_up(ri, 1);
  if (c == 0) { ex = 0.0f; ey = 0.0f; }
  csum[idx] = make_float2(ex, ey);
}

__global__ __launch_bounds__(256) void scan_apply(
    float2* __restrict__ P, const float2* __restrict__ csum) {
  const int chunk = blockIdx.x;
  const int batch = blockIdx.y >> 1;
  const int f = (blockIdx.y & 1) * 256 + threadIdx.x;
  float2 off = csum[((long)batch * CH + chunk) * 512 + f];
  float ar = off.x, ai = off.y;
  long base = ((long)batch * SS + (long)chunk * RR) * 512 + f;
  #pragma unroll
  for (int i0 = 0; i0 < RR; i0 += 8) {
    float2 p[8];
    #pragma unroll
    for (int j = 0; j < 8; ++j) p[j] = P[base + (long)(i0 + j) * 512];
    #pragma unroll
    for (int j = 0; j < 8; ++j) {
      ar += p[j].x; ai += p[j].y;
      P[base + (long)(i0 + j) * 512] = make_float2(ar, ai);
    }
  }
}

// ---------------------------------------------------------------------------
// Unbind, 2 rows/block (in place on d_out). mem rows Hermitian-packed;
// unpack into LDS, gather with predicated conj; one fwd FFT (q0+iq1),
// one inv FFT (z0+iz1).
// ---------------------------------------------------------------------------
__global__ __launch_bounds__(256) void unbind_kernel(
    float* __restrict__ qout, const float2* __restrict__ mem) {
  __shared__ float2 buf[BUFSZ];
  __shared__ float2 m0s[MEMSZ], m1s[MEMSZ];
  const int t = threadIdx.x;
  const long r0 = (long)blockIdx.x * 2;
  float* row0 = qout + r0 * DD;
  float* row1 = row0 + DD;
  const float2* mem0 = mem + r0 * 512;
  const float2* mem1 = mem0 + 512;

  float2 x[4];
  #pragma unroll
  for (int n = 0; n < 4; ++n) {
    const int i = t + 256 * n;
    x[n] = make_float2(row0[i], row1[i]);        // q0 + i*q1
  }
  #pragma unroll
  for (int n = 0; n < 2; ++n) {
    const int s = t + 256 * n;
    const float2 a = mem0[s], b = mem1[s];
    if (s == 0) {
      m0s[pidx16(0)]   = make_float2(a.x, 0.0f);
      m0s[pidx16(512)] = make_float2(a.y, 0.0f);
      m1s[pidx16(0)]   = make_float2(b.x, 0.0f);
      m1s[pidx16(512)] = make_float2(b.y, 0.0f);
    } else {
      m0s[pidx16(s)] = a;
      m1s[pidx16(s)] = b;
    }
  }
  fwd_fft(buf, x, t);   // internal barriers order the m*s writes too

  float2 z[4];
  #pragma unroll
  for (int m = 0; m < 4; ++m) {
    const int p   = t + 256 * m;
    const int bin = rev4(p);
    const int p2  = rev4((1024 - bin) & 1023);
    const float2 F1 = buf[pidx(p)], F2 = buf[pidx(p2)];
    const float q0r = 0.5f * (F1.x + F2.x), q0i = 0.5f * (F1.y - F2.y);
    const float q1r = 0.5f * (F1.y + F2.y), q1i = 0.5f * (F2.x - F1.x);
    const int  ix = (bin <= 512) ? bin : 1024 - bin;
    const float sg = (bin <= 512) ? 1.0f : -1.0f;
    float2 m0 = m0s[pidx16(ix)], m1 = m1s[pidx16(ix)];
    m0.y *= sg; m1.y *= sg;
    const float z0r = m0.x * q0r + m0.y * q0i, z0i = m0.y * q0r - m0.x * q0i;
    const float z1r = m1.x * q1r + m1.y * q1i, z1i = m1.y * q1r - m1.x * q1i;
    z[m] = make_float2(z0r - z1i, z0i + z1r);    // z0 + i*z1
  }
  __syncthreads();
  #pragma unroll
  for (int m = 0; m < 4; ++m) buf[pidx(t + 256 * m)] = z[m];
  __syncthreads();
  #pragma unroll
  for (int n = 0; n < 4; ++n) x[n] = buf[pidx(4 * t + n)];

  inv_stage<1>(x, t);   xchg<1, 4>(buf, x, t);
  inv_stage<4>(x, t);   xchg<4, 16>(buf, x, t);
  inv_stage<16>(x, t);  xchg<16, 64>(buf, x, t);
  inv_stage<64>(x, t);  xchg<64, 256>(buf, x, t);
  inv_stage<256>(x, t);

  const float sc = 1.0f / 1024.0f;
  #pragma unroll
  for (int n = 0; n < 4; ++n) {
    const int i = t + 256 * n;
    row0[i] = x[n].x * sc;
    row1[i] = x[n].y * sc;
  }
}

// ---------------------------------------------------------------------------
extern "C" void kernel_launch(void* const* d_in, const int* in_sizes, int n_in,
                              void* d_out, int out_size, void* d_ws, size_t ws_size,
                              hipStream_t stream) {
  (void)in_sizes; (void)n_in; (void)out_size;
  const float* x  = (const float*)d_in[0];
  const float* Wq = (const float*)d_in[1];
  const float* Wk = (const float*)d_in[2];
  const float* Wv = (const float*)d_in[3];
  float* out = (float*)d_out;

  // ws layout for MH rows/pass, nB batches/pass:
  //   Wb   : 3*1024*1024 bf16       = 6.29 MB
  //   xb   : MH*1024 bf16
  //   KV/P : MH rows * 4 KB
  //   csum : nB*64*512 float2
  // Single-pass (MH=8192): 57.67 MB; two-pass (MH=4096): 32.0 MB. Branch on
  // ws_size — constant across calls, so graph-safe.
  const size_t wbytes = (size_t)3 * DD * DD * 2;
  auto need = [&](size_t MHr, size_t nB) {
    return wbytes + MHr * DD * 2 + MHr * 4096 + nB * CH * 512 * 8;
  };
  const int nPass = (ws_size >= need(8192, 4)) ? 1 : 2;
  const size_t MH = MM / nPass;          // rows per pass
  const int    nB = BB / nPass;          // batches per pass

  char* ws = (char*)d_ws;
  unsigned short* Wb = (unsigned short*)ws;
  unsigned short* xb = (unsigned short*)(ws + wbytes);
  unsigned short* KV = (unsigned short*)(ws + wbytes + MH * DD * 2);
  float2*       csum = (float2*)((char*)KV + MH * 4096);

  convert_w<<<dim3(DD * DD / 1024, 3), 256, 0, stream>>>(Wq, Wk, Wv, Wb);

  for (int h = 0; h < nPass; ++h) {
    const float* xh   = x   + (size_t)h * MH * DD;
    float*       outh = out + (size_t)h * MH * DD;

    convert_bf16<<<MH * DD / 1024, 256, 0, stream>>>(xh, xb);
    gemm_mfma<<<dim3(MH / 128, DD / 128, 3), dim3(256), 0, stream>>>(xb, Wb, outh, KV);
    bind_kernel<<<MH, 256, 0, stream>>>(KV);
    scan_chunk_sum<<<dim3(CH, nB * 2), 256, 0, stream>>>((const float2*)KV, csum);
    scan_chunk_scan<<<nB * 128, 256, 0, stream>>>(csum);
    scan_apply<<<dim3(CH, nB * 2), 256, 0, stream>>>((float2*)KV, csum);
    unbind_kernel<<<MH / 2, 256, 0, stream>>>(outh, (const float2*)KV);
  }
}

// Round 11
// 220.641 us; speedup vs baseline: 1.0450x; 1.0180x over previous
//
#include <hip/hip_runtime.h>

// Problem constants: B=4, S=2048, D=1024
#define BB 4
#define SS 2048
#define DD 1024
#define MM 8192               // total rows
#define CH 64                 // scan chunks per batch
#define RR 32                 // rows per chunk (CH*RR = SS)
#define PI_F 3.14159265358979323846f

typedef __attribute__((ext_vector_type(8))) short bf16x8;
typedef __attribute__((ext_vector_type(4))) float f32x4;

// ---------------------------------------------------------------------------
// fp32 <-> bf16 helpers (RNE)
// ---------------------------------------------------------------------------
__device__ __forceinline__ unsigned short f2bf(float f) {
  unsigned int u = __float_as_uint(f);
  u = (u + 0x7FFFu + ((u >> 16) & 1u)) >> 16;
  return (unsigned short)u;
}
__device__ __forceinline__ float bf2f(unsigned short h) {
  return __uint_as_float(((unsigned int)h) << 16);
}

__global__ __launch_bounds__(256) void convert_bf16(
    const float* __restrict__ src, unsigned short* __restrict__ dst) {
  const long i = ((long)blockIdx.x * 256 + threadIdx.x) * 4;
  const float4 v = *(const float4*)&src[i];
  ushort4 o;
  o.x = f2bf(v.x); o.y = f2bf(v.y); o.z = f2bf(v.z); o.w = f2bf(v.w);
  *(ushort4*)&dst[i] = o;
}

__global__ __launch_bounds__(256) void convert_w(
    const float* __restrict__ Wq, const float* __restrict__ Wk,
    const float* __restrict__ Wv, unsigned short* __restrict__ dst) {
  const int z = blockIdx.y;
  const float* src = (z == 0) ? Wq : (z == 1) ? Wk : Wv;
  const long i = ((long)blockIdx.x * 256 + threadIdx.x) * 4;
  const float4 v = *(const float4*)&src[i];
  ushort4 o;
  o.x = f2bf(v.x); o.y = f2bf(v.y); o.z = f2bf(v.z); o.w = f2bf(v.w);
  *(ushort4*)&dst[(size_t)z * DD * DD + i] = o;
}

// ---------------------------------------------------------------------------
// MFMA GEMM — 128x128 tile, BK=64, 4 waves (2M x 2N, 64x64 out/wave),
// 2-phase counted-vmcnt schedule at 2 blocks/CU (LDS 64 KB).
// [R6 structure — best measured. 4/8-barrier variants regressed; barrier
//  crossings (~275cy each) dominate. Frozen.]
// ---------------------------------------------------------------------------
__device__ __forceinline__ void async16(const void* g, void* l) {
  __builtin_amdgcn_global_load_lds(
      (const __attribute__((address_space(1))) void*)g,
      (__attribute__((address_space(3))) void*)l, 16, 0, 0);
}

#define GW(n)  asm volatile("s_waitcnt vmcnt(" #n ")" ::: "memory")
#define BAR()  asm volatile("s_barrier" ::: "memory")
#define SB0()  __builtin_amdgcn_sched_barrier(0)

#define STA(buf, i, T) async16(xb + (size_t)(m0 + 32 * (i)) * DD + (T) * 64 + sOff, \
                               &Als[(buf) * 8192 + (i) * 2048 + slot8])
#define STB(buf, i, T) async16(W + (size_t)(n0 + 32 * (i)) * DD + (T) * 64 + sOff, \
                               &Bls[(buf) * 8192 + (i) * 2048 + slot8])
#define LDA(buf) { _Pragma("unroll") for (int mt = 0; mt < 4; ++mt) { \
    af[mt][0] = *(const bf16x8*)&Als[(buf) * 8192 + aRd + mt * 1024 + qoff0]; \
    af[mt][1] = *(const bf16x8*)&Als[(buf) * 8192 + aRd + mt * 1024 + qoff1]; } }
#define LDB(buf, nt, bank) { \
    bank[0] = *(const bf16x8*)&Bls[(buf) * 8192 + bRd + (nt) * 1024 + qoff0]; \
    bank[1] = *(const bf16x8*)&Bls[(buf) * 8192 + bRd + (nt) * 1024 + qoff1]; }
#define MMA(nt, bank) { __builtin_amdgcn_s_setprio(1); \
    _Pragma("unroll") for (int mt = 0; mt < 4; ++mt) { \
      acc[mt][nt] = __builtin_amdgcn_mfma_f32_16x16x32_bf16(af[mt][0], bank[0], acc[mt][nt], 0, 0, 0); \
      acc[mt][nt] = __builtin_amdgcn_mfma_f32_16x16x32_bf16(af[mt][1], bank[1], acc[mt][nt], 0, 0, 0); } \
    __builtin_amdgcn_s_setprio(0); }

__global__ __launch_bounds__(256, 2) void gemm_mfma(
    const unsigned short* __restrict__ xb,
    const unsigned short* __restrict__ Wb,
    float* __restrict__ outq, unsigned short* __restrict__ KV) {
  const int z = blockIdx.z;
  const unsigned short* W = Wb + (size_t)z * DD * DD;

  __shared__ unsigned short Als[2 * 8192];   // 32 KB
  __shared__ unsigned short Bls[2 * 8192];   // 32 KB

  const int tid  = threadIdx.x;
  const int lane = tid & 63;
  const int w    = tid >> 6;          // wave 0..3
  const int wm   = w >> 1;            // M half (0..1)
  const int wn   = w & 1;             // N half (0..1)
  const int fr   = lane & 15;
  const int kq   = lane >> 4;

  const int m0 = blockIdx.x * 128;
  const int n0 = blockIdx.y * 128;

  // staging geometry: unit = 4 KB = 256 threads x 16 B; 32 rows x 64 cols
  const int srow  = tid >> 3;                  // row within 32-row unit
  const int sq    = (tid & 7) ^ (srow & 7);    // swizzled source quad
  const int slot8 = tid * 8;                   // shorts (lane-linear dest)
  const size_t sOff = (size_t)srow * DD + sq * 8;

  // read-side addressing (same XOR as stage-source swizzle)
  const int qoff0 = ((0 + kq) ^ (fr & 7)) * 8;
  const int qoff1 = ((4 + kq) ^ (fr & 7)) * 8;
  const int aRd = wm * 4096 + fr * 64;
  const int bRd = wn * 4096 + fr * 64;

  f32x4 acc[4][4] = {};
  bf16x8 af[4][2];
  bf16x8 bva[2], bvb[2];

  // Prologue: A(0)x4, B(0)x4, A(1)x4 — order defines the vmcnt queue.
  STA(0, 0, 0); STA(0, 1, 0); STA(0, 2, 0); STA(0, 3, 0);
  STB(0, 0, 0); STB(0, 1, 0); STB(0, 2, 0); STB(0, 3, 0);
  STA(1, 0, 1); STA(1, 1, 1); STA(1, 2, 1); STA(1, 3, 1);

  // Main loop: tiles 0..13 (NT=16), 2 phases/tile, vmcnt(4) once per tile.
  for (int T = 0; T < 14; ++T) {
    const int buf = T & 1;
    // Ph0
    SB0(); GW(4); BAR();
    LDB(buf, 0, bva);
    LDA(buf);
    LDB(buf, 1, bvb);
    STB(buf ^ 1, 0, T + 1); STB(buf ^ 1, 1, T + 1);
    STB(buf ^ 1, 2, T + 1); STB(buf ^ 1, 3, T + 1);
    MMA(0, bva);
    MMA(1, bvb);
    // Ph1
    SB0(); BAR();
    LDB(buf, 2, bva);
    LDB(buf, 3, bvb);
    STA(buf, 0, T + 2); STA(buf, 1, T + 2);
    STA(buf, 2, T + 2); STA(buf, 3, T + 2);
    MMA(2, bva);
    MMA(3, bvb);
  }
  // T = 14 (buf 0): Ph0 stages B(15); Ph1 stages nothing.
  SB0(); GW(4); BAR();
  LDB(0, 0, bva); LDA(0); LDB(0, 1, bvb);
  STB(1, 0, 15); STB(1, 1, 15); STB(1, 2, 15); STB(1, 3, 15);
  MMA(0, bva); MMA(1, bvb);
  SB0(); BAR();
  LDB(0, 2, bva); LDB(0, 3, bvb);
  MMA(2, bva); MMA(3, bvb);
  // T = 15 (buf 1): drain all outstanding stages, no new stages.
  SB0(); GW(0); BAR();
  LDB(1, 0, bva); LDA(1); LDB(1, 1, bvb);
  MMA(0, bva); MMA(1, bvb);
  SB0(); BAR();
  LDB(1, 2, bva); LDB(1, 3, bvb);
  MMA(2, bva); MMA(3, bvb);

  // Epilogue
  const int col = lane & 15;
  const int r0  = (lane >> 4) * 4;
  const int mBase = m0 + wm * 64;
  const int nBase = n0 + wn * 64;
  if (z == 0) {
    #pragma unroll
    for (int mt = 0; mt < 4; ++mt)
      #pragma unroll
      for (int nt = 0; nt < 4; ++nt)
        #pragma unroll
        for (int r = 0; r < 4; ++r)
          outq[(size_t)(mBase + mt * 16 + r0 + r) * DD + nBase + nt * 16 + col] =
              acc[mt][nt][r];
  } else {
    unsigned short* Ck = KV + (size_t)(z - 1) * DD;
    #pragma unroll
    for (int mt = 0; mt < 4; ++mt)
      #pragma unroll
      for (int nt = 0; nt < 4; ++nt)
        #pragma unroll
        for (int r = 0; r < 4; ++r)
          Ck[(size_t)(mBase + mt * 16 + r0 + r) * 2048 + nBase + nt * 16 + col] =
              f2bf(acc[mt][nt][r]);
  }
}

// ---------------------------------------------------------------------------
// Radix-4 FFT utilities.
// bf4 = the exact DIF butterfly + twiddle sequence of the proven fwd_stage
// (same op order -> bit-identical).
// ---------------------------------------------------------------------------
__device__ __forceinline__ int pidx(int i) { return i + (i >> 6); }
#define BUFSZ 1040
__device__ __forceinline__ int pidx16(int i) { return i + (i >> 4); }
#define MEMSZ 546   // 513 slots + pads

__device__ __forceinline__ int rev4(int p) {
  unsigned r = __brev((unsigned)p) >> 22;
  return (int)(((r & 0x155u) << 1) | ((r & 0x2AAu) >> 1));
}

__host__ __device__ constexpr int clog2(int s) {
  return (s == 256) ? 8 : (s == 64) ? 6 : (s == 16) ? 4 : (s == 4) ? 2 : 0;
}

__device__ __forceinline__ void bf4(float2& a, float2& b, float2& c, float2& d,
                                    float c1, float s1) {
  const float c2 = c1 * c1 - s1 * s1, s2 = 2.0f * c1 * s1;
  const float c3 = c1 * c2 - s1 * s2, s3 = c1 * s2 + s1 * c2;
  const float Ar = a.x + c.x, Ai = a.y + c.y;
  const float Br = b.x + d.x, Bi = b.y + d.y;
  const float Cr = a.x - c.x, Ci = a.y - c.y;
  const float dr = b.x - d.x, di = b.y - d.y;
  const float y1r = Cr + di, y1i = Ci - dr;
  const float y2r = Ar - Br, y2i = Ai - Bi;
  const float y3r = Cr - di, y3i = Ci + dr;
  a = make_float2(Ar + Br, Ai + Bi);
  b = make_float2(y1r * c1 - y1i * s1, y1r * s1 + y1i * c1);
  c = make_float2(y2r * c2 - y2i * s2, y2r * s2 + y2i * c2);
  d = make_float2(y3r * c3 - y3i * s3, y3r * s3 + y3i * c3);
}

template <int S>
__device__ __forceinline__ void fwd_stage(float2 x[4], int t) {
  float c1 = 1.0f, s1 = 0.0f;
  if (S > 1) {
    const int j = t & (S - 1);
    __sincosf(-2.0f * PI_F * (float)j / (float)(4 * S), &s1, &c1);
  }
  bf4(x[0], x[1], x[2], x[3], c1, s1);
}

template <int S>
__device__ __forceinline__ void inv_stage(float2 x[4], int t) {
  float c1 = 1.0f, s1 = 0.0f;
  if (S > 1) {
    const int j = t & (S - 1);
    __sincosf(2.0f * PI_F * (float)j / (float)(4 * S), &s1, &c1);
  }
  const float c2 = c1 * c1 - s1 * s1, s2 = 2.0f * c1 * s1;
  const float c3 = c1 * c2 - s1 * s2, s3 = c1 * s2 + s1 * c2;
  const float u0r = x[0].x,                   u0i = x[0].y;
  const float u1r = x[1].x * c1 - x[1].y * s1, u1i = x[1].x * s1 + x[1].y * c1;
  const float u2r = x[2].x * c2 - x[2].y * s2, u2i = x[2].x * s2 + x[2].y * c2;
  const float u3r = x[3].x * c3 - x[3].y * s3, u3i = x[3].x * s3 + x[3].y * c3;
  const float Er = u0r + u2r, Ei = u0i + u2i;
  const float Fr = u0r - u2r, Fi = u0i - u2i;
  const float Gr = u1r + u3r, Gi = u1i + u3i;
  const float Hr = u1r - u3r, Hi = u1i - u3i;
  x[0] = make_float2(Er + Gr, Ei + Gi);
  x[1] = make_float2(Fr - Hi, Fi + Hr);
  x[2] = make_float2(Er - Gr, Ei - Gi);
  x[3] = make_float2(Fr + Hi, Fi - Hr);
}

template <int SW, int SR>
__device__ __forceinline__ void xchg(float2* buf, float2 x[4], int t) {
  constexpr int LW2 = clog2(SW), LR = clog2(SR);
  #pragma unroll
  for (int n = 0; n < 4; ++n)
    buf[pidx(((t >> LW2) << (LW2 + 2)) + (t & (SW - 1)) + n * SW)] = x[n];
  __syncthreads();
  #pragma unroll
  for (int n = 0; n < 4; ++n)
    x[n] = buf[pidx(((t >> LR) << (LR + 2)) + (t & (SR - 1)) + n * SR)];
  __syncthreads();
}

__device__ __forceinline__ void fwd_fft(float2* buf, float2 x[4], int t) {
  fwd_stage<256>(x, t); xchg<256, 64>(buf, x, t);
  fwd_stage<64>(x, t);  xchg<64, 16>(buf, x, t);
  fwd_stage<16>(x, t);  xchg<16, 4>(buf, x, t);
  fwd_stage<4>(x, t);   xchg<4, 1>(buf, x, t);
  fwd_stage<1>(x, t);
  #pragma unroll
  for (int n = 0; n < 4; ++n) buf[pidx(4 * t + n)] = x[n];
  __syncthreads();
}

// ---------------------------------------------------------------------------
// Bind v2 — ONE WAVE PER ROW, ZERO BARRIERS. 64 lanes x 16 complex/lane.
// Ownership schedule (all butterflies identical math + twiddle exponents to
// the proven 256-thread version -> bit-identical output):
//   stride-64 ownership (n = l + 64j): stages S=256 (j_tw = l+64b),
//     S=64 (j_tw = l, 1 sincos reused x4) are lane-local.
//   exchange 1 (XOR swizzle f1 = q ^ (((q>>6)&3)<<2)) -> stride-4 ownership
//     (n = 64g + c + 4j, g = l>>2, c = l&3): S=16 (j_tw = c+4b),
//     S=4 (j_tw = c, 1 sincos) local.
//   exchange 2 (f2 = q ^ ((q>>4)&15)) -> consecutive-16 (n = 16l + i):
//     S=1 local; final store buf[pidx(n)] (same layout as old epilogue).
// All LDS wave-internal (in-order) — lgkmcnt(0) between phases as insurance.
// Both exchange swizzles hit the 8B/lane bank floor (4 accesses/bank).
// Block = 4 waves = 4 rows; LDS 4 x 1040 float2 = 33.3 KB -> 4 blocks/CU.
// ---------------------------------------------------------------------------
#define LKW() asm volatile("s_waitcnt lgkmcnt(0)" ::: "memory")

__global__ __launch_bounds__(256) void bind_kernel(unsigned short* __restrict__ KV) {
  __shared__ float2 rbufs[4][BUFSZ];
  const int l  = threadIdx.x & 63;
  const int wv = threadIdx.x >> 6;
  float2* rbuf = rbufs[wv];
  unsigned short* row = KV + ((long)blockIdx.x * 4 + wv) * 2048;

  float2 x[16];
  #pragma unroll
  for (int j = 0; j < 16; ++j) {
    const int n = l + 64 * j;
    x[j] = make_float2(bf2f(row[n]), bf2f(row[1024 + n]));   // k + i*v
  }

  // Stage S=256: butterflies {b, b+4, b+8, b+12}, twiddle j = l + 64b
  #pragma unroll
  for (int b = 0; b < 4; ++b) {
    float s1, c1;
    __sincosf(-2.0f * PI_F * (float)(l + 64 * b) / 1024.0f, &s1, &c1);
    bf4(x[b], x[b + 4], x[b + 8], x[b + 12], c1, s1);
  }
  // Stage S=64: butterflies {4b..4b+3}, twiddle j = l (one sincos)
  {
    float s1, c1;
    __sincosf(-2.0f * PI_F * (float)l / 256.0f, &s1, &c1);
    #pragma unroll
    for (int b = 0; b < 4; ++b)
      bf4(x[4 * b], x[4 * b + 1], x[4 * b + 2], x[4 * b + 3], c1, s1);
  }

  // Exchange 1: stride-64 -> stride-4 ownership (swizzle f1)
  #pragma unroll
  for (int j = 0; j < 16; ++j)
    rbuf[(l ^ ((j & 3) << 2)) + 64 * j] = x[j];
  LKW();
  const int g = l >> 2, cc = l & 3;
  #pragma unroll
  for (int j = 0; j < 16; ++j) {
    const int q = 64 * g + cc + 4 * j;
    x[j] = rbuf[q ^ (((q >> 6) & 3) << 2)];
  }

  // Stage S=16: butterflies {b, b+4, b+8, b+12}, twiddle j = cc + 4b
  #pragma unroll
  for (int b = 0; b < 4; ++b) {
    float s1, c1;
    __sincosf(-2.0f * PI_F * (float)(cc + 4 * b) / 64.0f, &s1, &c1);
    bf4(x[b], x[b + 4], x[b + 8], x[b + 12], c1, s1);
  }
  // Stage S=4: butterflies {4b..4b+3}, twiddle j = cc (one sincos)
  {
    float s1, c1;
    __sincosf(-2.0f * PI_F * (float)cc / 16.0f, &s1, &c1);
    #pragma unroll
    for (int b = 0; b < 4; ++b)
      bf4(x[4 * b], x[4 * b + 1], x[4 * b + 2], x[4 * b + 3], c1, s1);
  }

  // Exchange 2: stride-4 -> consecutive-16 ownership (swizzle f2)
  #pragma unroll
  for (int j = 0; j < 16; ++j) {
    const int q = 64 * g + cc + 4 * j;
    rbuf[q ^ ((q >> 4) & 15)] = x[j];
  }
  LKW();
  #pragma unroll
  for (int i = 0; i < 16; ++i) {
    const int q = 16 * l + i;
    x[i] = rbuf[q ^ ((q >> 4) & 15)];
  }

  // Stage S=1: butterflies {4b..4b+3}, no twiddle
  #pragma unroll
  for (int b = 0; b < 4; ++b)
    bf4(x[4 * b], x[4 * b + 1], x[4 * b + 2], x[4 * b + 3], 1.0f, 0.0f);

  // Final store at DIF in-place positions (same convention as old code)
  #pragma unroll
  for (int i = 0; i < 16; ++i)
    rbuf[pidx(16 * l + i)] = x[i];
  LKW();

  // Hermitian split + bind product; s = l + 64m, m in [0,8) -> s in [0,512)
  float2* Prow = (float2*)row;
  #pragma unroll
  for (int m = 0; m < 8; ++m) {
    const int s = l + 64 * m;
    if (s == 0) {
      const float2 W0   = rbuf[pidx(0)];
      const float2 W512 = rbuf[pidx(2)];
      Prow[0] = make_float2(W0.x * W0.y, W512.x * W512.y);
    } else {
      const int p1 = rev4(s);
      const int p2 = rev4(1024 - s);
      const float2 F1 = rbuf[pidx(p1)], F2 = rbuf[pidx(p2)];
      const float fkr = 0.5f * (F1.x + F2.x), fki = 0.5f * (F1.y - F2.y);
      const float fvr = 0.5f * (F1.y + F2.y), fvi = 0.5f * (F2.x - F1.x);
      Prow[s] = make_float2(fkr * fvr - fki * fvi, fkr * fvi + fki * fvr);
    }
  }
}

// ---------------------------------------------------------------------------
// Causal cumsum over s per packed bin; grids cover nB batches (gridDim.y=2*nB).
// Loads batched 8-deep (breaks dependent-latency chain); order preserved.
// ---------------------------------------------------------------------------
__global__ __launch_bounds__(256) void scan_chunk_sum(
    const float2* __restrict__ P, float2* __restrict__ csum) {
  const int chunk = blockIdx.x;
  const int batch = blockIdx.y >> 1;
  const int f = (blockIdx.y & 1) * 256 + threadIdx.x;
  long base = ((long)batch * SS + (long)chunk * RR) * 512 + f;
  float sr = 0.0f, si = 0.0f;
  #pragma unroll
  for (int i0 = 0; i0 < RR; i0 += 8) {
    float2 p[8];
    #pragma unroll
    for (int j = 0; j < 8; ++j) p[j] = P[base + (long)(i0 + j) * 512];
    #pragma unroll
    for (int j = 0; j < 8; ++j) { sr += p[j].x; si += p[j].y; }
  }
  csum[((long)batch * CH + chunk) * 512 + f] = make_float2(sr, si);
}

// Wave-parallel exclusive scan over the 64 chunks: one wave per (batch,bin)
// column, lane = chunk.
__global__ __launch_bounds__(256) void scan_chunk_scan(float2* csum) {
  const int col   = blockIdx.x * 4 + (threadIdx.x >> 6);  // (batch,f) column
  const int batch = col >> 9;
  const int f     = col & 511;
  const int c     = threadIdx.x & 63;                     // lane = chunk
  const long idx  = ((long)batch * CH + c) * 512 + f;
  const float2 v  = csum[idx];
  float rr = v.x, ri = v.y;
  #pragma unroll
  for (int d = 1; d < 64; d <<= 1) {
    const float ox = __shfl_up(rr, d);
    const float oy = __shfl_up(ri, d);
    if (c >= d) { rr += ox; ri += oy; }
  }
  // inclusive -> exclusive via lane shift
  float ex = __shfl_up(rr, 1);
  float ey = __shfl_up(ri, 1);
  if (c == 0) { ex = 0.0f; ey = 0.0f; }
  csum[idx] = make_float2(ex, ey);
}

__global__ __launch_bounds__(256) void scan_apply(
    float2* __restrict__ P, const float2* __restrict__ csum) {
  const int chunk = blockIdx.x;
  const int batch = blockIdx.y >> 1;
  const int f = (blockIdx.y & 1) * 256 + threadIdx.x;
  float2 off = csum[((long)batch * CH + chunk) * 512 + f];
  float ar = off.x, ai = off.y;
  long base = ((long)batch * SS + (long)chunk * RR) * 512 + f;
  #pragma unroll
  for (int i0 = 0; i0 < RR; i0 += 8) {
    float2 p[8];
    #pragma unroll
    for (int j = 0; j < 8; ++j) p[j] = P[base + (long)(i0 + j) * 512];
    #pragma unroll
    for (int j = 0; j < 8; ++j) {
      ar += p[j].x; ai += p[j].y;
      P[base + (long)(i0 + j) * 512] = make_float2(ar, ai);
    }
  }
}

// ---------------------------------------------------------------------------
// Unbind, 2 rows/block (in place on d_out). mem rows Hermitian-packed;
// unpack into LDS, gather with predicated conj; one fwd FFT (q0+iq1),
// one inv FFT (z0+iz1). [Unchanged this round — ports to the 1-wave
// structure next round if bind v2 wins.]
// ---------------------------------------------------------------------------
__global__ __launch_bounds__(256) void unbind_kernel(
    float* __restrict__ qout, const float2* __restrict__ mem) {
  __shared__ float2 buf[BUFSZ];
  __shared__ float2 m0s[MEMSZ], m1s[MEMSZ];
  const int t = threadIdx.x;
  const long r0 = (long)blockIdx.x * 2;
  float* row0 = qout + r0 * DD;
  float* row1 = row0 + DD;
  const float2* mem0 = mem + r0 * 512;
  const float2* mem1 = mem0 + 512;

  float2 x[4];
  #pragma unroll
  for (int n = 0; n < 4; ++n) {
    const int i = t + 256 * n;
    x[n] = make_float2(row0[i], row1[i]);        // q0 + i*q1
  }
  #pragma unroll
  for (int n = 0; n < 2; ++n) {
    const int s = t + 256 * n;
    const float2 a = mem0[s], b = mem1[s];
    if (s == 0) {
      m0s[pidx16(0)]   = make_float2(a.x, 0.0f);
      m0s[pidx16(512)] = make_float2(a.y, 0.0f);
      m1s[pidx16(0)]   = make_float2(b.x, 0.0f);
      m1s[pidx16(512)] = make_float2(b.y, 0.0f);
    } else {
      m0s[pidx16(s)] = a;
      m1s[pidx16(s)] = b;
    }
  }
  fwd_fft(buf, x, t);   // internal barriers order the m*s writes too

  float2 z[4];
  #pragma unroll
  for (int m = 0; m < 4; ++m) {
    const int p   = t + 256 * m;
    const int bin = rev4(p);
    const int p2  = rev4((1024 - bin) & 1023);
    const float2 F1 = buf[pidx(p)], F2 = buf[pidx(p2)];
    const float q0r = 0.5f * (F1.x + F2.x), q0i = 0.5f * (F1.y - F2.y);
    const float q1r = 0.5f * (F1.y + F2.y), q1i = 0.5f * (F2.x - F1.x);
    const int  ix = (bin <= 512) ? bin : 1024 - bin;
    const float sg = (bin <= 512) ? 1.0f : -1.0f;
    float2 m0 = m0s[pidx16(ix)], m1 = m1s[pidx16(ix)];
    m0.y *= sg; m1.y *= sg;
    const float z0r = m0.x * q0r + m0.y * q0i, z0i = m0.y * q0r - m0.x * q0i;
    const float z1r = m1.x * q1r + m1.y * q1i, z1i = m1.y * q1r - m1.x * q1i;
    z[m] = make_float2(z0r - z1i, z0i + z1r);    // z0 + i*z1
  }
  __syncthreads();
  #pragma unroll
  for (int m = 0; m < 4; ++m) buf[pidx(t + 256 * m)] = z[m];
  __syncthreads();
  #pragma unroll
  for (int n = 0; n < 4; ++n) x[n] = buf[pidx(4 * t + n)];

  inv_stage<1>(x, t);   xchg<1, 4>(buf, x, t);
  inv_stage<4>(x, t);   xchg<4, 16>(buf, x, t);
  inv_stage<16>(x, t);  xchg<16, 64>(buf, x, t);
  inv_stage<64>(x, t);  xchg<64, 256>(buf, x, t);
  inv_stage<256>(x, t);

  const float sc = 1.0f / 1024.0f;
  #pragma unroll
  for (int n = 0; n < 4; ++n) {
    const int i = t + 256 * n;
    row0[i] = x[n].x * sc;
    row1[i] = x[n].y * sc;
  }
}

// ---------------------------------------------------------------------------
extern "C" void kernel_launch(void* const* d_in, const int* in_sizes, int n_in,
                              void* d_out, int out_size, void* d_ws, size_t ws_size,
                              hipStream_t stream) {
  (void)in_sizes; (void)n_in; (void)out_size;
  const float* x  = (const float*)d_in[0];
  const float* Wq = (const float*)d_in[1];
  const float* Wk = (const float*)d_in[2];
  const float* Wv = (const float*)d_in[3];
  float* out = (float*)d_out;

  // ws layout for MH rows/pass, nB batches/pass:
  //   Wb   : 3*1024*1024 bf16       = 6.29 MB
  //   xb   : MH*1024 bf16
  //   KV/P : MH rows * 4 KB
  //   csum : nB*64*512 float2
  // Single-pass (MH=8192): 57.67 MB; two-pass (MH=4096): 32.0 MB. Branch on
  // ws_size — constant across calls, so graph-safe.
  const size_t wbytes = (size_t)3 * DD * DD * 2;
  auto need = [&](size_t MHr, size_t nB) {
    return wbytes + MHr * DD * 2 + MHr * 4096 + nB * CH * 512 * 8;
  };
  const int nPass = (ws_size >= need(8192, 4)) ? 1 : 2;
  const size_t MH = MM / nPass;          // rows per pass
  const int    nB = BB / nPass;          // batches per pass

  char* ws = (char*)d_ws;
  unsigned short* Wb = (unsigned short*)ws;
  unsigned short* xb = (unsigned short*)(ws + wbytes);
  unsigned short* KV = (unsigned short*)(ws + wbytes + MH * DD * 2);
  float2*       csum = (float2*)((char*)KV + MH * 4096);

  convert_w<<<dim3(DD * DD / 1024, 3), 256, 0, stream>>>(Wq, Wk, Wv, Wb);

  for (int h = 0; h < nPass; ++h) {
    const float* xh   = x   + (size_t)h * MH * DD;
    float*       outh = out + (size_t)h * MH * DD;

    convert_bf16<<<MH * DD / 1024, 256, 0, stream>>>(xh, xb);
    gemm_mfma<<<dim3(MH / 128, DD / 128, 3), dim3(256), 0, stream>>>(xb, Wb, outh, KV);
    bind_kernel<<<MH / 4, 256, 0, stream>>>(KV);
    scan_chunk_sum<<<dim3(CH, nB * 2), 256, 0, stream>>>((const float2*)KV, csum);
    scan_chunk_scan<<<nB * 128, 256, 0, stream>>>(csum);
    scan_apply<<<dim3(CH, nB * 2), 256, 0, stream>>>((float2*)KV, csum);
    unbind_kernel<<<MH / 2, 256, 0, stream>>>(outh, (const float2*)KV);
  }
}

// Round 12
// 219.699 us; speedup vs baseline: 1.0495x; 1.0043x over previous
//
#include <hip/hip_runtime.h>

// Problem constants: B=4, S=2048, D=1024
#define BB 4
#define SS 2048
#define DD 1024
#define MM 8192               // total rows
#define CH 64                 // scan chunks per batch
#define RR 32                 // rows per chunk (CH*RR = SS)
#define PI_F 3.14159265358979323846f

typedef __attribute__((ext_vector_type(8))) short bf16x8;
typedef __attribute__((ext_vector_type(4))) float f32x4;

// ---------------------------------------------------------------------------
// fp32 <-> bf16 helpers (RNE)
// ---------------------------------------------------------------------------
__device__ __forceinline__ unsigned short f2bf(float f) {
  unsigned int u = __float_as_uint(f);
  u = (u + 0x7FFFu + ((u >> 16) & 1u)) >> 16;
  return (unsigned short)u;
}
__device__ __forceinline__ float bf2f(unsigned short h) {
  return __uint_as_float(((unsigned int)h) << 16);
}

__global__ __launch_bounds__(256) void convert_bf16(
    const float* __restrict__ src, unsigned short* __restrict__ dst) {
  const long i = ((long)blockIdx.x * 256 + threadIdx.x) * 4;
  const float4 v = *(const float4*)&src[i];
  ushort4 o;
  o.x = f2bf(v.x); o.y = f2bf(v.y); o.z = f2bf(v.z); o.w = f2bf(v.w);
  *(ushort4*)&dst[i] = o;
}

__global__ __launch_bounds__(256) void convert_w(
    const float* __restrict__ Wq, const float* __restrict__ Wk,
    const float* __restrict__ Wv, unsigned short* __restrict__ dst) {
  const int z = blockIdx.y;
  const float* src = (z == 0) ? Wq : (z == 1) ? Wk : Wv;
  const long i = ((long)blockIdx.x * 256 + threadIdx.x) * 4;
  const float4 v = *(const float4*)&src[i];
  ushort4 o;
  o.x = f2bf(v.x); o.y = f2bf(v.y); o.z = f2bf(v.z); o.w = f2bf(v.w);
  *(ushort4*)&dst[(size_t)z * DD * DD + i] = o;
}

// ---------------------------------------------------------------------------
// MFMA GEMM — 128x128 tile, BK=64, 4 waves (2M x 2N, 64x64 out/wave),
// 2-phase counted-vmcnt schedule at 2 blocks/CU (LDS 64 KB).
// [R6 structure — best measured. Frozen.]
// ---------------------------------------------------------------------------
__device__ __forceinline__ void async16(const void* g, void* l) {
  __builtin_amdgcn_global_load_lds(
      (const __attribute__((address_space(1))) void*)g,
      (__attribute__((address_space(3))) void*)l, 16, 0, 0);
}

#define GW(n)  asm volatile("s_waitcnt vmcnt(" #n ")" ::: "memory")
#define BAR()  asm volatile("s_barrier" ::: "memory")
#define SB0()  __builtin_amdgcn_sched_barrier(0)

#define STA(buf, i, T) async16(xb + (size_t)(m0 + 32 * (i)) * DD + (T) * 64 + sOff, \
                               &Als[(buf) * 8192 + (i) * 2048 + slot8])
#define STB(buf, i, T) async16(W + (size_t)(n0 + 32 * (i)) * DD + (T) * 64 + sOff, \
                               &Bls[(buf) * 8192 + (i) * 2048 + slot8])
#define LDA(buf) { _Pragma("unroll") for (int mt = 0; mt < 4; ++mt) { \
    af[mt][0] = *(const bf16x8*)&Als[(buf) * 8192 + aRd + mt * 1024 + qoff0]; \
    af[mt][1] = *(const bf16x8*)&Als[(buf) * 8192 + aRd + mt * 1024 + qoff1]; } }
#define LDB(buf, nt, bank) { \
    bank[0] = *(const bf16x8*)&Bls[(buf) * 8192 + bRd + (nt) * 1024 + qoff0]; \
    bank[1] = *(const bf16x8*)&Bls[(buf) * 8192 + bRd + (nt) * 1024 + qoff1]; }
#define MMA(nt, bank) { __builtin_amdgcn_s_setprio(1); \
    _Pragma("unroll") for (int mt = 0; mt < 4; ++mt) { \
      acc[mt][nt] = __builtin_amdgcn_mfma_f32_16x16x32_bf16(af[mt][0], bank[0], acc[mt][nt], 0, 0, 0); \
      acc[mt][nt] = __builtin_amdgcn_mfma_f32_16x16x32_bf16(af[mt][1], bank[1], acc[mt][nt], 0, 0, 0); } \
    __builtin_amdgcn_s_setprio(0); }

__global__ __launch_bounds__(256, 2) void gemm_mfma(
    const unsigned short* __restrict__ xb,
    const unsigned short* __restrict__ Wb,
    float* __restrict__ outq, unsigned short* __restrict__ KV) {
  const int z = blockIdx.z;
  const unsigned short* W = Wb + (size_t)z * DD * DD;

  __shared__ unsigned short Als[2 * 8192];   // 32 KB
  __shared__ unsigned short Bls[2 * 8192];   // 32 KB

  const int tid  = threadIdx.x;
  const int lane = tid & 63;
  const int w    = tid >> 6;          // wave 0..3
  const int wm   = w >> 1;            // M half (0..1)
  const int wn   = w & 1;             // N half (0..1)
  const int fr   = lane & 15;
  const int kq   = lane >> 4;

  const int m0 = blockIdx.x * 128;
  const int n0 = blockIdx.y * 128;

  // staging geometry: unit = 4 KB = 256 threads x 16 B; 32 rows x 64 cols
  const int srow  = tid >> 3;                  // row within 32-row unit
  const int sq    = (tid & 7) ^ (srow & 7);    // swizzled source quad
  const int slot8 = tid * 8;                   // shorts (lane-linear dest)
  const size_t sOff = (size_t)srow * DD + sq * 8;

  // read-side addressing (same XOR as stage-source swizzle)
  const int qoff0 = ((0 + kq) ^ (fr & 7)) * 8;
  const int qoff1 = ((4 + kq) ^ (fr & 7)) * 8;
  const int aRd = wm * 4096 + fr * 64;
  const int bRd = wn * 4096 + fr * 64;

  f32x4 acc[4][4] = {};
  bf16x8 af[4][2];
  bf16x8 bva[2], bvb[2];

  // Prologue: A(0)x4, B(0)x4, A(1)x4 — order defines the vmcnt queue.
  STA(0, 0, 0); STA(0, 1, 0); STA(0, 2, 0); STA(0, 3, 0);
  STB(0, 0, 0); STB(0, 1, 0); STB(0, 2, 0); STB(0, 3, 0);
  STA(1, 0, 1); STA(1, 1, 1); STA(1, 2, 1); STA(1, 3, 1);

  // Main loop: tiles 0..13 (NT=16), 2 phases/tile, vmcnt(4) once per tile.
  for (int T = 0; T < 14; ++T) {
    const int buf = T & 1;
    // Ph0
    SB0(); GW(4); BAR();
    LDB(buf, 0, bva);
    LDA(buf);
    LDB(buf, 1, bvb);
    STB(buf ^ 1, 0, T + 1); STB(buf ^ 1, 1, T + 1);
    STB(buf ^ 1, 2, T + 1); STB(buf ^ 1, 3, T + 1);
    MMA(0, bva);
    MMA(1, bvb);
    // Ph1
    SB0(); BAR();
    LDB(buf, 2, bva);
    LDB(buf, 3, bvb);
    STA(buf, 0, T + 2); STA(buf, 1, T + 2);
    STA(buf, 2, T + 2); STA(buf, 3, T + 2);
    MMA(2, bva);
    MMA(3, bvb);
  }
  // T = 14 (buf 0): Ph0 stages B(15); Ph1 stages nothing.
  SB0(); GW(4); BAR();
  LDB(0, 0, bva); LDA(0); LDB(0, 1, bvb);
  STB(1, 0, 15); STB(1, 1, 15); STB(1, 2, 15); STB(1, 3, 15);
  MMA(0, bva); MMA(1, bvb);
  SB0(); BAR();
  LDB(0, 2, bva); LDB(0, 3, bvb);
  MMA(2, bva); MMA(3, bvb);
  // T = 15 (buf 1): drain all outstanding stages, no new stages.
  SB0(); GW(0); BAR();
  LDB(1, 0, bva); LDA(1); LDB(1, 1, bvb);
  MMA(0, bva); MMA(1, bvb);
  SB0(); BAR();
  LDB(1, 2, bva); LDB(1, 3, bvb);
  MMA(2, bva); MMA(3, bvb);

  // Epilogue
  const int col = lane & 15;
  const int r0  = (lane >> 4) * 4;
  const int mBase = m0 + wm * 64;
  const int nBase = n0 + wn * 64;
  if (z == 0) {
    #pragma unroll
    for (int mt = 0; mt < 4; ++mt)
      #pragma unroll
      for (int nt = 0; nt < 4; ++nt)
        #pragma unroll
        for (int r = 0; r < 4; ++r)
          outq[(size_t)(mBase + mt * 16 + r0 + r) * DD + nBase + nt * 16 + col] =
              acc[mt][nt][r];
  } else {
    unsigned short* Ck = KV + (size_t)(z - 1) * DD;
    #pragma unroll
    for (int mt = 0; mt < 4; ++mt)
      #pragma unroll
      for (int nt = 0; nt < 4; ++nt)
        #pragma unroll
        for (int r = 0; r < 4; ++r)
          Ck[(size_t)(mBase + mt * 16 + r0 + r) * 2048 + nBase + nt * 16 + col] =
              f2bf(acc[mt][nt][r]);
  }
}

// ---------------------------------------------------------------------------
// Radix-4 FFT butterflies. bf4 = forward DIF (twiddle outputs),
// ibf4 = inverse DIT (twiddle inputs) — exact op sequences of the proven
// fwd_stage/inv_stage -> bit-identical values.
// ---------------------------------------------------------------------------
__device__ __forceinline__ int pidx(int i) { return i + (i >> 6); }
#define BUFSZ 1040

__device__ __forceinline__ int rev4(int p) {
  unsigned r = __brev((unsigned)p) >> 22;
  return (int)(((r & 0x155u) << 1) | ((r & 0x2AAu) >> 1));
}

__device__ __forceinline__ void bf4(float2& a, float2& b, float2& c, float2& d,
                                    float c1, float s1) {
  const float c2 = c1 * c1 - s1 * s1, s2 = 2.0f * c1 * s1;
  const float c3 = c1 * c2 - s1 * s2, s3 = c1 * s2 + s1 * c2;
  const float Ar = a.x + c.x, Ai = a.y + c.y;
  const float Br = b.x + d.x, Bi = b.y + d.y;
  const float Cr = a.x - c.x, Ci = a.y - c.y;
  const float dr = b.x - d.x, di = b.y - d.y;
  const float y1r = Cr + di, y1i = Ci - dr;
  const float y2r = Ar - Br, y2i = Ai - Bi;
  const float y3r = Cr - di, y3i = Ci + dr;
  a = make_float2(Ar + Br, Ai + Bi);
  b = make_float2(y1r * c1 - y1i * s1, y1r * s1 + y1i * c1);
  c = make_float2(y2r * c2 - y2i * s2, y2r * s2 + y2i * c2);
  d = make_float2(y3r * c3 - y3i * s3, y3r * s3 + y3i * c3);
}

__device__ __forceinline__ void ibf4(float2& a, float2& b, float2& c, float2& d,
                                     float c1, float s1) {
  const float c2 = c1 * c1 - s1 * s1, s2 = 2.0f * c1 * s1;
  const float c3 = c1 * c2 - s1 * s2, s3 = c1 * s2 + s1 * c2;
  const float u0r = a.x,                 u0i = a.y;
  const float u1r = b.x * c1 - b.y * s1, u1i = b.x * s1 + b.y * c1;
  const float u2r = c.x * c2 - c.y * s2, u2i = c.x * s2 + c.y * c2;
  const float u3r = d.x * c3 - d.y * s3, u3i = d.x * s3 + d.y * c3;
  const float Er = u0r + u2r, Ei = u0i + u2i;
  const float Fr = u0r - u2r, Fi = u0i - u2i;
  const float Gr = u1r + u3r, Gi = u1i + u3i;
  const float Hr = u1r - u3r, Hi = u1i - u3i;
  a = make_float2(Er + Gr, Ei + Gi);
  b = make_float2(Fr - Hi, Fi + Hr);
  c = make_float2(Er - Gr, Ei - Gi);
  d = make_float2(Fr + Hi, Fi - Hr);
}

#define LKW() asm volatile("s_waitcnt lgkmcnt(0)" ::: "memory")

// Wave-local forward FFT, 64 lanes x 16 complex in x[], rbuf = per-wave LDS.
// Ownership: stride-64 [S=256,S=64] -> exch f1 -> stride-4 [S=16,S=4]
// -> exch f2 -> consecutive-16 [S=1]; result stored rbuf[pidx(n)].
// HW-verified in bind v2 (R11).
__device__ __forceinline__ void wave_fwd_fft(float2* rbuf, float2 x[16], int l) {
  #pragma unroll
  for (int b = 0; b < 4; ++b) {
    float s1, c1;
    __sincosf(-2.0f * PI_F * (float)(l + 64 * b) / 1024.0f, &s1, &c1);
    bf4(x[b], x[b + 4], x[b + 8], x[b + 12], c1, s1);
  }
  {
    float s1, c1;
    __sincosf(-2.0f * PI_F * (float)l / 256.0f, &s1, &c1);
    #pragma unroll
    for (int b = 0; b < 4; ++b)
      bf4(x[4 * b], x[4 * b + 1], x[4 * b + 2], x[4 * b + 3], c1, s1);
  }
  #pragma unroll
  for (int j = 0; j < 16; ++j)
    rbuf[(l ^ ((j & 3) << 2)) + 64 * j] = x[j];
  LKW();
  const int g = l >> 2, cc = l & 3;
  #pragma unroll
  for (int j = 0; j < 16; ++j) {
    const int q = 64 * g + cc + 4 * j;
    x[j] = rbuf[q ^ (((q >> 6) & 3) << 2)];
  }
  #pragma unroll
  for (int b = 0; b < 4; ++b) {
    float s1, c1;
    __sincosf(-2.0f * PI_F * (float)(cc + 4 * b) / 64.0f, &s1, &c1);
    bf4(x[b], x[b + 4], x[b + 8], x[b + 12], c1, s1);
  }
  {
    float s1, c1;
    __sincosf(-2.0f * PI_F * (float)cc / 16.0f, &s1, &c1);
    #pragma unroll
    for (int b = 0; b < 4; ++b)
      bf4(x[4 * b], x[4 * b + 1], x[4 * b + 2], x[4 * b + 3], c1, s1);
  }
  #pragma unroll
  for (int j = 0; j < 16; ++j) {
    const int q = 64 * g + cc + 4 * j;
    rbuf[q ^ ((q >> 4) & 15)] = x[j];
  }
  LKW();
  #pragma unroll
  for (int i = 0; i < 16; ++i) {
    const int q = 16 * l + i;
    x[i] = rbuf[q ^ ((q >> 4) & 15)];
  }
  #pragma unroll
  for (int b = 0; b < 4; ++b)
    bf4(x[4 * b], x[4 * b + 1], x[4 * b + 2], x[4 * b + 3], 1.0f, 0.0f);
  #pragma unroll
  for (int i = 0; i < 16; ++i)
    rbuf[pidx(16 * l + i)] = x[i];
  LKW();
}

// ---------------------------------------------------------------------------
// Bind v2 — one wave per row, zero barriers (HW-verified R11).
// ---------------------------------------------------------------------------
__global__ __launch_bounds__(256) void bind_kernel(unsigned short* __restrict__ KV) {
  __shared__ float2 rbufs[4][BUFSZ];
  const int l  = threadIdx.x & 63;
  const int wv = threadIdx.x >> 6;
  float2* rbuf = rbufs[wv];
  unsigned short* row = KV + ((long)blockIdx.x * 4 + wv) * 2048;

  float2 x[16];
  #pragma unroll
  for (int j = 0; j < 16; ++j) {
    const int n = l + 64 * j;
    x[j] = make_float2(bf2f(row[n]), bf2f(row[1024 + n]));   // k + i*v
  }
  wave_fwd_fft(rbuf, x, l);

  // Hermitian split + bind product; s = l + 64m, m in [0,8) -> s in [0,512)
  float2* Prow = (float2*)row;
  #pragma unroll
  for (int m = 0; m < 8; ++m) {
    const int s = l + 64 * m;
    if (s == 0) {
      const float2 W0   = rbuf[pidx(0)];
      const float2 W512 = rbuf[pidx(2)];
      Prow[0] = make_float2(W0.x * W0.y, W512.x * W512.y);
    } else {
      const int p1 = rev4(s);
      const int p2 = rev4(1024 - s);
      const float2 F1 = rbuf[pidx(p1)], F2 = rbuf[pidx(p2)];
      const float fkr = 0.5f * (F1.x + F2.x), fki = 0.5f * (F1.y - F2.y);
      const float fvr = 0.5f * (F1.y + F2.y), fvi = 0.5f * (F2.x - F1.x);
      Prow[s] = make_float2(fkr * fvr - fki * fvi, fkr * fvi + fki * fvr);
    }
  }
}

// ---------------------------------------------------------------------------
// Causal cumsum over s per packed bin; grids cover nB batches (gridDim.y=2*nB).
// ---------------------------------------------------------------------------
__global__ __launch_bounds__(256) void scan_chunk_sum(
    const float2* __restrict__ P, float2* __restrict__ csum) {
  const int chunk = blockIdx.x;
  const int batch = blockIdx.y >> 1;
  const int f = (blockIdx.y & 1) * 256 + threadIdx.x;
  long base = ((long)batch * SS + (long)chunk * RR) * 512 + f;
  float sr = 0.0f, si = 0.0f;
  #pragma unroll
  for (int i0 = 0; i0 < RR; i0 += 8) {
    float2 p[8];
    #pragma unroll
    for (int j = 0; j < 8; ++j) p[j] = P[base + (long)(i0 + j) * 512];
    #pragma unroll
    for (int j = 0; j < 8; ++j) { sr += p[j].x; si += p[j].y; }
  }
  csum[((long)batch * CH + chunk) * 512 + f] = make_float2(sr, si);
}

// Wave-parallel exclusive scan over the 64 chunks: one wave per (batch,bin)
// column, lane = chunk.
__global__ __launch_bounds__(256) void scan_chunk_scan(float2* csum) {
  const int col   = blockIdx.x * 4 + (threadIdx.x >> 6);  // (batch,f) column
  const int batch = col >> 9;
  const int f     = col & 511;
  const int c     = threadIdx.x & 63;                     // lane = chunk
  const long idx  = ((long)batch * CH + c) * 512 + f;
  const float2 v  = csum[idx];
  float rr = v.x, ri = v.y;
  #pragma unroll
  for (int d = 1; d < 64; d <<= 1) {
    const float ox = __shfl_up(rr, d);
    const float oy = __shfl_up(ri, d);
    if (c >= d) { rr += ox; ri += oy; }
  }
  // inclusive -> exclusive via lane shift
  float ex = __shfl_up(rr, 1);
  float ey = __shfl_up(ri, 1);
  if (c == 0) { ex = 0.0f; ey = 0.0f; }
  csum[idx] = make_float2(ex, ey);
}

__global__ __launch_bounds__(256) void scan_apply(
    float2* __restrict__ P, const float2* __restrict__ csum) {
  const int chunk = blockIdx.x;
  const int batch = blockIdx.y >> 1;
  const int f = (blockIdx.y & 1) * 256 + threadIdx.x;
  float2 off = csum[((long)batch * CH + chunk) * 512 + f];
  float ar = off.x, ai = off.y;
  long base = ((long)batch * SS + (long)chunk * RR) * 512 + f;
  #pragma unroll
  for (int i0 = 0; i0 < RR; i0 += 8) {
    float2 p[8];
    #pragma unroll
    for (int j = 0; j < 8; ++j) p[j] = P[base + (long)(i0 + j) * 512];
    #pragma unroll
    for (int j = 0; j < 8; ++j) {
      ar += p[j].x; ai += p[j].y;
      P[base + (long)(i0 + j) * 512] = make_float2(ar, ai);
    }
  }
}

// ---------------------------------------------------------------------------
// Unbind v2 — one wave per 2 rows (q0 + i*q1), zero barriers.
// Forward = wave_fwd_fft (HW-verified). Hermitian split + multiply gathers
// mem DIRECTLY from global (L2-resident 4 KB rows; ix/sg logic identical to
// the old m0s/m1s staging). z lands at consecutive-16 ownership = exactly
// the inverse DIT's entry ownership -> no LDS round-trip for z.
// Inverse schedule (mirror of forward, twiddles/groupings verified vs old
// inv_stage chain stage-by-stage -> bit-identical):
//   consecutive-16 [S=1] -> exch f2 -> stride-4 [S=4 (tw cc/16),
//   S=16 (tw (cc+4b)/64)] -> exch f1 -> stride-64 [S=64 (tw l/256),
//   S=256 (tw (l+64c2)/1024)]; output n = l + 64j coalesced.
// Block = 4 waves = 8 rows; LDS 33.3 KB -> 4 blocks/CU.
// ---------------------------------------------------------------------------
__global__ __launch_bounds__(256) void unbind_kernel(
    float* __restrict__ qout, const float2* __restrict__ mem) {
  __shared__ float2 rbufs[4][BUFSZ];
  const int l  = threadIdx.x & 63;
  const int wv = threadIdx.x >> 6;
  float2* rbuf = rbufs[wv];
  const long r0 = ((long)blockIdx.x * 4 + wv) * 2;
  float* row0 = qout + r0 * DD;
  float* row1 = row0 + DD;
  const float2* mem0 = mem + r0 * 512;
  const float2* mem1 = mem0 + 512;

  float2 x[16];
  #pragma unroll
  for (int j = 0; j < 16; ++j) {
    const int n = l + 64 * j;
    x[j] = make_float2(row0[n], row1[n]);        // q0 + i*q1
  }
  wave_fwd_fft(rbuf, x, l);

  // Hermitian split + unbind multiply; p = 16l + i (consecutive-16).
  #pragma unroll
  for (int i = 0; i < 16; ++i) {
    const int p   = 16 * l + i;
    const int bin = rev4(p);
    const int p2  = rev4((1024 - bin) & 1023);
    const float2 F1 = rbuf[pidx(p)], F2 = rbuf[pidx(p2)];
    const float q0r = 0.5f * (F1.x + F2.x), q0i = 0.5f * (F1.y - F2.y);
    const float q1r = 0.5f * (F1.y + F2.y), q1i = 0.5f * (F2.x - F1.x);
    const int   ix = (bin <= 512) ? bin : 1024 - bin;
    const float sg = (bin <= 512) ? 1.0f : -1.0f;
    float2 m0, m1;
    if (ix == 0) {
      m0 = make_float2(mem0[0].x, 0.0f); m1 = make_float2(mem1[0].x, 0.0f);
    } else if (ix == 512) {
      m0 = make_float2(mem0[0].y, 0.0f); m1 = make_float2(mem1[0].y, 0.0f);
    } else {
      m0 = mem0[ix]; m1 = mem1[ix];
      m0.y *= sg; m1.y *= sg;
    }
    const float z0r = m0.x * q0r + m0.y * q0i, z0i = m0.y * q0r - m0.x * q0i;
    const float z1r = m1.x * q1r + m1.y * q1i, z1i = m1.y * q1r - m1.x * q1i;
    x[i] = make_float2(z0r - z1i, z0i + z1r);    // z0 + i*z1
  }

  // Inverse FFT. consecutive-16: S=1 (no twiddle).
  #pragma unroll
  for (int b = 0; b < 4; ++b)
    ibf4(x[4 * b], x[4 * b + 1], x[4 * b + 2], x[4 * b + 3], 1.0f, 0.0f);

  // exch f2: consecutive-16 -> stride-4
  #pragma unroll
  for (int i = 0; i < 16; ++i) {
    const int q = 16 * l + i;
    rbuf[q ^ ((q >> 4) & 15)] = x[i];
  }
  LKW();
  const int g = l >> 2, cc = l & 3;
  #pragma unroll
  for (int j = 0; j < 16; ++j) {
    const int q = 64 * g + cc + 4 * j;
    x[j] = rbuf[q ^ ((q >> 4) & 15)];
  }

  // stride-4: S=4 (tw cc/16, butterflies x[4b..4b+3])
  {
    float s1, c1;
    __sincosf(2.0f * PI_F * (float)cc / 16.0f, &s1, &c1);
    #pragma unroll
    for (int b = 0; b < 4; ++b)
      ibf4(x[4 * b], x[4 * b + 1], x[4 * b + 2], x[4 * b + 3], c1, s1);
  }
  // S=16 (tw (cc+4b)/64, butterflies x[b], x[b+4], x[b+8], x[b+12])
  #pragma unroll
  for (int b = 0; b < 4; ++b) {
    float s1, c1;
    __sincosf(2.0f * PI_F * (float)(cc + 4 * b) / 64.0f, &s1, &c1);
    ibf4(x[b], x[b + 4], x[b + 8], x[b + 12], c1, s1);
  }

  // exch f1: stride-4 -> stride-64
  #pragma unroll
  for (int j = 0; j < 16; ++j) {
    const int q = 64 * g + cc + 4 * j;
    rbuf[q ^ (((q >> 6) & 3) << 2)] = x[j];
  }
  LKW();
  #pragma unroll
  for (int j = 0; j < 16; ++j) {
    const int q = l + 64 * j;
    x[j] = rbuf[q ^ (((q >> 6) & 3) << 2)];
  }

  // stride-64: S=64 (tw l/256, butterflies x[4b..4b+3])
  {
    float s1, c1;
    __sincosf(2.0f * PI_F * (float)l / 256.0f, &s1, &c1);
    #pragma unroll
    for (int b = 0; b < 4; ++b)
      ibf4(x[4 * b], x[4 * b + 1], x[4 * b + 2], x[4 * b + 3], c1, s1);
  }
  // S=256 (tw (l+64c2)/1024, butterflies x[c2], x[c2+4], x[c2+8], x[c2+12])
  #pragma unroll
  for (int c2 = 0; c2 < 4; ++c2) {
    float s1, c1;
    __sincosf(2.0f * PI_F * (float)(l + 64 * c2) / 1024.0f, &s1, &c1);
    ibf4(x[c2], x[c2 + 4], x[c2 + 8], x[c2 + 12], c1, s1);
  }

  // Output: n = l + 64j, coalesced per j.
  const float sc = 1.0f / 1024.0f;
  #pragma unroll
  for (int j = 0; j < 16; ++j) {
    const int n = l + 64 * j;
    row0[n] = x[j].x * sc;
    row1[n] = x[j].y * sc;
  }
}

// ---------------------------------------------------------------------------
extern "C" void kernel_launch(void* const* d_in, const int* in_sizes, int n_in,
                              void* d_out, int out_size, void* d_ws, size_t ws_size,
                              hipStream_t stream) {
  (void)in_sizes; (void)n_in; (void)out_size;
  const float* x  = (const float*)d_in[0];
  const float* Wq = (const float*)d_in[1];
  const float* Wk = (const float*)d_in[2];
  const float* Wv = (const float*)d_in[3];
  float* out = (float*)d_out;

  // ws layout for MH rows/pass, nB batches/pass:
  //   Wb   : 3*1024*1024 bf16       = 6.29 MB
  //   xb   : MH*1024 bf16
  //   KV/P : MH rows * 4 KB
  //   csum : nB*64*512 float2
  // Single-pass (MH=8192): 57.67 MB; two-pass (MH=4096): 32.0 MB. Branch on
  // ws_size — constant across calls, so graph-safe.
  const size_t wbytes = (size_t)3 * DD * DD * 2;
  auto need = [&](size_t MHr, size_t nB) {
    return wbytes + MHr * DD * 2 + MHr * 4096 + nB * CH * 512 * 8;
  };
  const int nPass = (ws_size >= need(8192, 4)) ? 1 : 2;
  const size_t MH = MM / nPass;          // rows per pass
  const int    nB = BB / nPass;          // batches per pass

  char* ws = (char*)d_ws;
  unsigned short* Wb = (unsigned short*)ws;
  unsigned short* xb = (unsigned short*)(ws + wbytes);
  unsigned short* KV = (unsigned short*)(ws + wbytes + MH * DD * 2);
  float2*       csum = (float2*)((char*)KV + MH * 4096);

  convert_w<<<dim3(DD * DD / 1024, 3), 256, 0, stream>>>(Wq, Wk, Wv, Wb);

  for (int h = 0; h < nPass; ++h) {
    const float* xh   = x   + (size_t)h * MH * DD;
    float*       outh = out + (size_t)h * MH * DD;

    convert_bf16<<<MH * DD / 1024, 256, 0, stream>>>(xh, xb);
    gemm_mfma<<<dim3(MH / 128, DD / 128, 3), dim3(256), 0, stream>>>(xb, Wb, outh, KV);
    bind_kernel<<<MH / 4, 256, 0, stream>>>(KV);
    scan_chunk_sum<<<dim3(CH, nB * 2), 256, 0, stream>>>((const float2*)KV, csum);
    scan_chunk_scan<<<nB * 128, 256, 0, stream>>>(csum);
    scan_apply<<<dim3(CH, nB * 2), 256, 0, stream>>>((float2*)KV, csum);
    unbind_kernel<<<MH / 8, 256, 0, stream>>>(outh, (const float2*)KV);
  }
}